// Round 4
// baseline (68200.781 us; speedup 1.0000x reference)
//
#include <hip/hip_runtime.h>
#include <stdint.h>

#define B_    512
#define SEQ_  256
#define H_    512
#define NSEQH (SEQ_ * H_)
#define NBLK  256
#define NTHR  (NBLK * 256)

using f32x4 = __attribute__((ext_vector_type(4))) float;
using s16x8 = __attribute__((ext_vector_type(8))) short;

__device__ inline unsigned short f2bf(float f) {
  union { float f; uint32_t u; } x; x.f = f;
  uint32_t u = x.u;
  uint32_t r = u + 0x7fffu + ((u >> 16) & 1u);
  return (unsigned short)(r >> 16);
}
__device__ inline float bf2f(unsigned short h) {
  union { float f; uint32_t u; } x; x.u = ((uint32_t)h) << 16;
  return x.f;
}
__device__ inline float h2f(unsigned short u) {
  _Float16 h; __builtin_memcpy(&h, &u, 2); return (float)h;
}
__device__ inline unsigned short f2h(float f) {
  _Float16 h = (_Float16)f; unsigned short u; __builtin_memcpy(&u, &h, 2); return u;
}
__device__ inline float sigf(float x) { return 1.0f / (1.0f + expf(-x)); }

__device__ inline void gload16(const void* g, void* l) {
  __builtin_amdgcn_global_load_lds(
      (const __attribute__((address_space(1))) void*)g,
      (__attribute__((address_space(3))) void*)l, 16, 0, 0);
}

// sense-reversing grid barrier, agent scope (release flushes XCD L2,
// acquire invalidates stale lines -> cross-XCD visibility of plain stores)
__device__ __forceinline__ void gbar(unsigned* bar) {
  __syncthreads();
  if (threadIdx.x == 0) {
    unsigned g = __hip_atomic_load(bar + 1, __ATOMIC_RELAXED, __HIP_MEMORY_SCOPE_AGENT);
    unsigned a = __hip_atomic_fetch_add(bar, 1u, __ATOMIC_ACQ_REL, __HIP_MEMORY_SCOPE_AGENT);
    if (a == (unsigned)(NBLK - 1)) {
      __hip_atomic_store(bar, 0u, __ATOMIC_RELAXED, __HIP_MEMORY_SCOPE_AGENT);
      __hip_atomic_store(bar + 1, g + 1u, __ATOMIC_RELEASE, __HIP_MEMORY_SCOPE_AGENT);
    } else {
      while (__hip_atomic_load(bar + 1, __ATOMIC_ACQUIRE, __HIP_MEMORY_SCOPE_AGENT) == g)
        __builtin_amdgcn_s_sleep(2);
    }
  }
  __syncthreads();
}

__global__ void fill_kernel(float* __restrict__ out, int n, float v) {
  int i = blockIdx.x * blockDim.x + threadIdx.x;
  if (i < n) out[i] = v;
}

// ---------------------------------------------------------------------------
// G1 phase: h_upd = h + Tm1*tanh(h @ Wd.T + bd). 32x32 tile/block,
// blk -> (m=blk>>4, n=blk&15)  [same-n blocks share XCD blk%8 = n%8].
// K' = 3*512 = 24 tiles of 64. Depth-3 LDS pipeline, counted vmcnt.
// CVT (layer1): also convert lo0 fp16 slab -> xh hi/lo for G2.
// ---------------------------------------------------------------------------
template<bool CVT>
__device__ __forceinline__ void g1_phase(
    char (*As)[8192], char (*Bs)[8192],
    const short* hhi, const short* hlo,
    const short* Wds, const float* bd,
    const float* hbuf, const float* tm1,
    short* huhi, short* hulo,
    const unsigned short* lo0_t, short* xhhi, short* xhlo)
{
  const int tid = threadIdx.x;
  const int blk = blockIdx.x;
  const int n0 = (blk & 15) * 32;
  const int m0 = (blk >> 4) * 32;
  const int w = tid >> 6, l = tid & 63;
  const int sr = tid >> 3;
  const int scs = (tid & 7) ^ (sr & 7);

  f32x4 acc = {0.f, 0.f, 0.f, 0.f};

  auto stage = [&](int kt) {
    const int buf = kt % 3;
    const int blkk = kt >> 3;
    const int kk = (kt & 7) << 6;
    const short* Asrc = (blkk == 1) ? hlo : hhi;
    const int boff = kk + ((blkk == 2) ? 512 : 0);
    gload16(Asrc + (size_t)(m0 + sr) * H_ + kk + scs * 8, (char*)As[buf] + w * 1024);
    gload16(Wds + (size_t)(n0 + sr) * 1024 + boff + scs * 8, (char*)Bs[buf] + w * 1024);
  };

  stage(0); stage(1);

  const int wm = w & 1, wn = w >> 1;
  const int ar = wm * 16 + (l & 15);
  const int br = wn * 16 + (l & 15);
  const int koff = (l >> 4) * 16;
  const int aswz = (ar & 7) << 4;
  const int bswz = (br & 7) << 4;

  for (int kt = 0; kt < 24; ++kt) {
    const int buf = kt % 3;
    if (kt < 23) { asm volatile("s_waitcnt vmcnt(2)" ::: "memory"); }
    else         { asm volatile("s_waitcnt vmcnt(0)" ::: "memory"); }
    __syncthreads();
    if (kt + 2 < 24) stage(kt + 2);
#pragma unroll
    for (int k2 = 0; k2 < 2; ++k2) {
      s16x8 af = *(const s16x8*)(As[buf] + ((ar * 128 + k2 * 64 + koff) ^ aswz));
      s16x8 bf = *(const s16x8*)(Bs[buf] + ((br * 128 + k2 * 64 + koff) ^ bswz));
      acc = __builtin_amdgcn_mfma_f32_16x16x32_bf16(af, bf, acc, 0, 0, 0);
    }
  }

  const int n_abs = n0 + wn * 16 + (l & 15);
  const int mbase = m0 + wm * 16 + (l >> 4) * 4;
  const float bv = bd[n_abs];
#pragma unroll
  for (int r = 0; r < 4; ++r) {
    const int m_abs = mbase + r;
    float cst = tanhf(acc[r] + bv);
    float hu = hbuf[(size_t)m_abs * H_ + n_abs] + tm1[m_abs] * cst;
    unsigned short hi = f2bf(hu);
    huhi[(size_t)m_abs * H_ + n_abs] = (short)hi;
    hulo[(size_t)m_abs * H_ + n_abs] = (short)f2bf(hu - bf2f(hi));
    if (CVT) {
      float xv = h2f(lo0_t[(size_t)m_abs * NSEQH + n_abs]);
      unsigned short xh = f2bf(xv);
      xhhi[(size_t)m_abs * H_ + n_abs] = (short)xh;
      xhlo[(size_t)m_abs * H_ + n_abs] = (short)f2bf(xv - bf2f(xh));
    }
  }
}

// ---------------------------------------------------------------------------
// G2 phase: z = [x,h_upd] @ W.T + b -> cell update. 64m x (16j x 4gates)
// per block; blk -> (m=blk>>5, j=blk&31) [same-j blocks share XCD j%8].
// K' = 3K tiles of 64; depth-3 pipeline, counted vmcnt(4).
// ---------------------------------------------------------------------------
template<int K, int TPB, int KPS, int XK, int XSTR, bool STORE_LO0>
__device__ __forceinline__ void g2_phase(
    char (*As)[8192], char (*Bs)[8192],
    const short* xhi, const short* xlo,
    const short* huhi, const short* hulo,
    const short* Wsp, const float* bias,
    float* cbuf, float* hbuf, short* hhi, short* hlo,
    unsigned short* lo0_t)
{
  constexpr int NT = 3 * K / 64;
  const int tid = threadIdx.x;
  const int blk = blockIdx.x;
  const int j0 = (blk & 31) * 16;
  const int m0 = (blk >> 5) * 64;
  const int w = tid >> 6, l = tid & 63;

  f32x4 acc[4];
#pragma unroll
  for (int i = 0; i < 4; ++i) acc[i] = (f32x4){0.f, 0.f, 0.f, 0.f};

  auto stage = [&](int kt) {
    const int buf = kt % 3;
    const int blkk = kt / TPB;
    const int kk = (kt - blkk * TPB) << 6;
    const bool lo_a = (blkk == 1);
    const int boff = kk + ((blkk == 2) ? K : 0);
#pragma unroll
    for (int j = 0; j < 2; ++j) {
      const int s = tid + j * 256;
      const int r = s >> 3;
      const int cs = (s & 7) ^ (r & 7);
      const short* asrc; size_t aoff;
      if (kk < XK) { asrc = lo_a ? xlo : xhi; aoff = (size_t)(m0 + r) * XSTR + kk + cs * 8; }
      else         { asrc = lo_a ? hulo : huhi; aoff = (size_t)(m0 + r) * H_ + (kk - XK) + cs * 8; }
      gload16(asrc + aoff, (char*)As[buf] + j * 4096 + w * 1024);
      const int src_n = (r >> 4) * H_ + j0 + (r & 15);
      gload16(Wsp + (size_t)src_n * KPS + boff + cs * 8, (char*)Bs[buf] + j * 4096 + w * 1024);
    }
  };

  stage(0); stage(1);

  const int ar = w * 16 + (l & 15);
  const int koff = (l >> 4) * 16;
  const int aswz = (ar & 7) << 4;

  for (int kt = 0; kt < NT; ++kt) {
    const int buf = kt % 3;
    if (kt < NT - 1) { asm volatile("s_waitcnt vmcnt(4)" ::: "memory"); }
    else             { asm volatile("s_waitcnt vmcnt(0)" ::: "memory"); }
    __syncthreads();
    if (kt + 2 < NT) stage(kt + 2);
#pragma unroll
    for (int k2 = 0; k2 < 2; ++k2) {
      s16x8 af = *(const s16x8*)(As[buf] + ((ar * 128 + k2 * 64 + koff) ^ aswz));
#pragma unroll
      for (int nf = 0; nf < 4; ++nf) {
        const int br = nf * 16 + (l & 15);
        s16x8 bf = *(const s16x8*)(Bs[buf] + ((br * 128 + k2 * 64 + koff) ^ ((br & 7) << 4)));
        acc[nf] = __builtin_amdgcn_mfma_f32_16x16x32_bf16(af, bf, acc[nf], 0, 0, 0);
      }
    }
  }

  const int j_abs = j0 + (l & 15);
  const float bi  = bias[j_abs];
  const float bfv = bias[H_ + j_abs];
  const float bo  = bias[2 * H_ + j_abs];
  const float bg  = bias[3 * H_ + j_abs];
#pragma unroll
  for (int r = 0; r < 4; ++r) {
    const int m_abs = m0 + w * 16 + (l >> 4) * 4 + r;
    float zi = acc[0][r] + bi;
    float zf = acc[1][r] + bfv;
    float zo = acc[2][r] + bo;
    float zg = acc[3][r] + bg;
    float co = cbuf[(size_t)m_abs * H_ + j_abs];
    float cn = sigf(zf) * co + sigf(zi) * tanhf(zg);
    float hn = sigf(zo) * tanhf(cn);
    cbuf[(size_t)m_abs * H_ + j_abs] = cn;
    hbuf[(size_t)m_abs * H_ + j_abs] = hn;
    unsigned short hi = f2bf(hn);
    hhi[(size_t)m_abs * H_ + j_abs] = (short)hi;
    hlo[(size_t)m_abs * H_ + j_abs] = (short)f2bf(hn - bf2f(hi));
    if (STORE_LO0)
      lo0_t[(size_t)m_abs * NSEQH + j_abs] = f2h(hn);
  }
}

// ---------------------------------------------------------------------------
// Persistent kernel: prep + both layers x 256 steps + output copy.
// ---------------------------------------------------------------------------
__global__ __launch_bounds__(256, 1) void persist(
    const float* inputs,
    const float* W0, const float* b0, const float* Wd0, const float* bd0,
    const float* W1, const float* b1, const float* Wd1, const float* bd1,
    float* out,
    unsigned short* lo0, short* xinhi, short* xinlo,
    float* hbuf, float* cbuf,
    short* hhi, short* hlo, short* huhi, short* hulo,
    short* xhhi, short* xhlo,
    float* Tm1T, short* Wd0s, short* Wd1s, short* W0s, short* W1s,
    unsigned* bar)
{
  __shared__ __align__(16) char As[3][8192];
  __shared__ __align__(16) char Bs[3][8192];
  const int gtid = blockIdx.x * 256 + threadIdx.x;

  // ---- prologue: weight splits, x split, Tm1, state zero ----
  auto dosplit = [&](const float* W, short* Ws, int N, int Ksrc, int Kpad, int pad_at) {
    const int total = N * Kpad;
    for (int idx = gtid; idx < total; idx += NTHR) {
      int n = idx / Kpad, c = idx - n * Kpad;
      int sc = c;
      if (pad_at >= 0) { if (c == pad_at) sc = -1; else if (c > pad_at) sc = c - 1; }
      float v = 0.f;
      if (sc >= 0 && sc < Ksrc) v = W[(size_t)n * Ksrc + sc];
      unsigned short hi = f2bf(v);
      unsigned short lo = f2bf(v - bf2f(hi));
      size_t base = (size_t)n * (2 * Kpad);
      Ws[base + c]        = (short)hi;
      Ws[base + Kpad + c] = (short)lo;
    }
  };
  dosplit(Wd0, Wd0s, 512, 512, 512, -1);
  dosplit(Wd1, Wd1s, 512, 512, 512, -1);
  dosplit(W0, W0s, 2048, 575, 576, 63);
  dosplit(W1, W1s, 2048, 1024, 1024, -1);
  for (int idx = gtid; idx < B_ * SEQ_ * 64; idx += NTHR) {
    float v = inputs[idx];
    unsigned short hi = f2bf(v);
    xinhi[idx] = (short)hi;
    xinlo[idx] = (short)f2bf(v - bf2f(hi));
  }
  for (int idx = gtid; idx < B_ * SEQ_; idx += NTHR) {
    int b = idx / SEQ_, t = idx - b * SEQ_;
    float dt = inputs[(size_t)b * (SEQ_ * 64) + t * 64 + 63];
    Tm1T[t * B_ + b] = 1.0f / logf(dt + 2.7183f) - 1.0f;
  }
  for (int idx = gtid; idx < B_ * H_; idx += NTHR) {
    hbuf[idx] = 0.f; cbuf[idx] = 0.f; hhi[idx] = 0; hlo[idx] = 0;
  }
  gbar(bar);

  for (int layer = 0; layer < 2; ++layer) {
    if (layer == 1) {
      for (int idx = gtid; idx < B_ * H_; idx += NTHR) {
        hbuf[idx] = 0.f; cbuf[idx] = 0.f; hhi[idx] = 0; hlo[idx] = 0;
      }
      gbar(bar);
    }
    for (int s = 0; s < SEQ_; ++s) {
      const int torig = SEQ_ - 1 - s;
      if (layer == 0) {
        g1_phase<false>(As, Bs, hhi, hlo, Wd0s, bd0, hbuf,
                        Tm1T + (size_t)torig * B_, huhi, hulo,
                        nullptr, nullptr, nullptr);
        gbar(bar);
        g2_phase<576, 9, 1152, 64, SEQ_ * 64, true>(
            As, Bs, xinhi + (size_t)torig * 64, xinlo + (size_t)torig * 64,
            huhi, hulo, W0s, b0, cbuf, hbuf, hhi, hlo,
            lo0 + (size_t)s * H_);
        gbar(bar);
      } else {
        g1_phase<true>(As, Bs, hhi, hlo, Wd1s, bd1, hbuf,
                       Tm1T + (size_t)torig * B_, huhi, hulo,
                       lo0 + (size_t)torig * H_, xhhi, xhlo);
        gbar(bar);
        g2_phase<1024, 16, 2048, 512, H_, false>(
            As, Bs, xhhi, xhlo, huhi, hulo, W1s, b1,
            cbuf, hbuf, hhi, hlo, nullptr);
        gbar(bar);
      }
    }
  }

  for (int idx = gtid; idx < B_ * H_; idx += NTHR) out[idx] = hbuf[idx];
}

extern "C" void kernel_launch(void* const* d_in, const int* in_sizes, int n_in,
                              void* d_out, int out_size, void* d_ws, size_t ws_size,
                              hipStream_t stream) {
  const float* inputs = (const float*)d_in[0];
  const float* W0  = (const float*)d_in[1];
  const float* b0  = (const float*)d_in[2];
  const float* Wd0 = (const float*)d_in[3];
  const float* bd0 = (const float*)d_in[4];
  const float* W1  = (const float*)d_in[5];
  const float* b1  = (const float*)d_in[6];
  const float* Wd1 = (const float*)d_in[7];
  const float* bd1 = (const float*)d_in[8];

  char* ws = (char*)d_ws;
  size_t off = 0;
  auto alloc = [&](size_t bytes) -> char* {
    char* p = ws + off;
    off += (bytes + 1023) & ~(size_t)1023;
    return p;
  };
  unsigned* bar = (unsigned*)alloc(1024);
  unsigned short* lo0 = (unsigned short*)alloc((size_t)B_ * SEQ_ * H_ * 2); // fp16
  short* xinhi = (short*)alloc((size_t)B_ * SEQ_ * 64 * 2);
  short* xinlo = (short*)alloc((size_t)B_ * SEQ_ * 64 * 2);
  float* hbuf  = (float*)alloc((size_t)B_ * H_ * 4);
  float* cbuf  = (float*)alloc((size_t)B_ * H_ * 4);
  short* hhi   = (short*)alloc((size_t)B_ * H_ * 2);
  short* hlo   = (short*)alloc((size_t)B_ * H_ * 2);
  short* huhi  = (short*)alloc((size_t)B_ * H_ * 2);
  short* hulo  = (short*)alloc((size_t)B_ * H_ * 2);
  short* xhhi  = (short*)alloc((size_t)B_ * H_ * 2);
  short* xhlo  = (short*)alloc((size_t)B_ * H_ * 2);
  float* Tm1T  = (float*)alloc((size_t)SEQ_ * B_ * 4);
  short* Wd0s  = (short*)alloc((size_t)512 * 1024 * 2);
  short* Wd1s  = (short*)alloc((size_t)512 * 1024 * 2);
  short* W0s   = (short*)alloc((size_t)2048 * 1152 * 2);
  short* W1s   = (short*)alloc((size_t)2048 * 2048 * 2);

  if (off > ws_size) {
    fill_kernel<<<(out_size + 255) / 256, 256, 0, stream>>>(
        (float*)d_out, out_size, (float)(ws_size >> 20));
    return;
  }

  hipMemsetAsync(bar, 0, 64, stream);
  persist<<<NBLK, 256, 0, stream>>>(
      inputs, W0, b0, Wd0, bd0, W1, b1, Wd1, bd1,
      (float*)d_out,
      lo0, xinhi, xinlo, hbuf, cbuf,
      hhi, hlo, huhi, hulo, xhhi, xhlo,
      Tm1T, Wd0s, Wd1s, W0s, W1s, bar);
}

// Round 6
// 42673.129 us; speedup vs baseline: 1.5982x; 1.5982x over previous
//
#include <hip/hip_runtime.h>
#include <stdint.h>

#define B_    512
#define SEQ_  256
#define H_    512
#define NSEQH (SEQ_ * H_)
#define NBLK  256
#define NTHR  (NBLK * 256)

using f32x4 = __attribute__((ext_vector_type(4))) float;
using s16x8 = __attribute__((ext_vector_type(8))) short;

__device__ inline unsigned short f2bf(float f) {
  union { float f; uint32_t u; } x; x.f = f;
  uint32_t u = x.u;
  uint32_t r = u + 0x7fffu + ((u >> 16) & 1u);
  return (unsigned short)(r >> 16);
}
__device__ inline float bf2f(unsigned short h) {
  union { float f; uint32_t u; } x; x.u = ((uint32_t)h) << 16;
  return x.f;
}
__device__ inline float h2f(unsigned short u) {
  _Float16 h; __builtin_memcpy(&h, &u, 2); return (float)h;
}
__device__ inline unsigned short f2h(float f) {
  _Float16 h = (_Float16)f; unsigned short u; __builtin_memcpy(&u, &h, 2); return u;
}
__device__ inline float sigf(float x) { return 1.0f / (1.0f + expf(-x)); }

// async global->LDS, cached (weights: read-only)
__device__ inline void gload16(const void* g, void* l) {
  __builtin_amdgcn_global_load_lds(
      (const __attribute__((address_space(1))) void*)g,
      (__attribute__((address_space(3))) void*)l, 16, 0, 0);
}
// async global->LDS, coherent (sc0|sc1 = 1|16): bypasses stale per-XCD L2.
// No register destination -> no compiler async-reg hazard.
__device__ inline void gload16c(const void* g, void* l) {
  __builtin_amdgcn_global_load_lds(
      (const __attribute__((address_space(1))) void*)g,
      (__attribute__((address_space(3))) void*)l, 16, 0, 17);
}

// coherent scalar helpers: compiler-managed sc0sc1 + waitcnt
__device__ __forceinline__ float ldf_coh(const float* p) {
  return __hip_atomic_load(p, __ATOMIC_RELAXED, __HIP_MEMORY_SCOPE_SYSTEM);
}
__device__ __forceinline__ unsigned short ldh_coh(const unsigned short* p) {
  return __hip_atomic_load(p, __ATOMIC_RELAXED, __HIP_MEMORY_SCOPE_SYSTEM);
}
__device__ __forceinline__ void stf_coh(float* p, float v) {
  __hip_atomic_store(p, v, __ATOMIC_RELAXED, __HIP_MEMORY_SCOPE_SYSTEM);
}
__device__ __forceinline__ void sth_coh(short* p, unsigned short v) {
  __hip_atomic_store((unsigned short*)p, v, __ATOMIC_RELAXED, __HIP_MEMORY_SCOPE_SYSTEM);
}

// heavy barrier (agent acq_rel -> L2 writeback+invalidate). Used ONCE after
// the prologue to publish weights/x-splits for normal cached reads.
__device__ __forceinline__ void gbar_heavy(unsigned* bar) {
  __syncthreads();
  if (threadIdx.x == 0) {
    unsigned g = __hip_atomic_load(bar + 1, __ATOMIC_RELAXED, __HIP_MEMORY_SCOPE_AGENT);
    unsigned a = __hip_atomic_fetch_add(bar, 1u, __ATOMIC_ACQ_REL, __HIP_MEMORY_SCOPE_AGENT);
    if (a == (unsigned)(NBLK - 1)) {
      __hip_atomic_store(bar, 0u, __ATOMIC_RELAXED, __HIP_MEMORY_SCOPE_AGENT);
      __hip_atomic_store(bar + 1, g + 1u, __ATOMIC_RELEASE, __HIP_MEMORY_SCOPE_AGENT);
    } else {
      while (__hip_atomic_load(bar + 1, __ATOMIC_ACQUIRE, __HIP_MEMORY_SCOPE_AGENT) == g)
        __builtin_amdgcn_s_sleep(2);
    }
  }
  __syncthreads();
}

// light barrier: NO cache maintenance. Data is published by sc0sc1 stores
// (drained by the vmcnt(0) in __syncthreads); flags are relaxed system
// atomics at the coherent point. 2-level tree: 8 leaves of 32 + root.
__device__ __forceinline__ void lbar(unsigned* bar, int& nb) {
  __syncthreads();
  ++nb;
  if (threadIdx.x == 0) {
    unsigned* leaf = bar + 32 + (blockIdx.x >> 5) * 32;
    unsigned* root = bar + 8;
    unsigned old = __hip_atomic_fetch_add(leaf, 1u, __ATOMIC_RELAXED, __HIP_MEMORY_SCOPE_SYSTEM);
    if ((old & 31u) == 31u)
      __hip_atomic_fetch_add(root, 1u, __ATOMIC_RELAXED, __HIP_MEMORY_SCOPE_SYSTEM);
    const unsigned target = (unsigned)(8 * nb);
    while ((int)(__hip_atomic_load(root, __ATOMIC_RELAXED, __HIP_MEMORY_SCOPE_SYSTEM) - target) < 0)
      __builtin_amdgcn_s_sleep(1);
  }
  __syncthreads();
}

__global__ void fill_kernel(float* __restrict__ out, int n, float v) {
  int i = blockIdx.x * blockDim.x + threadIdx.x;
  if (i < n) out[i] = v;
}

// ---------------------------------------------------------------------------
// G1: h_upd = h + Tm1*tanh(h @ Wd.T + bd). 32x32 tile, blk->(n=blk&15,m=blk>>4)
// [same-n blocks -> same XCD: Wd slice L2-warm]. K'=3*512 = 24 tiles of 64.
// A: coherent gload_lds (h splits change every step); B: cached gload_lds.
// Both pre-swizzled source chunks, swizzled ds_read (R4-proven pattern).
// ---------------------------------------------------------------------------
template<bool CVT>
__device__ __forceinline__ void g1_phase(
    char (*As)[8192], char (*Bs)[8192],
    const short* hhi, const short* hlo,
    const short* Wds, const float* bd,
    const float* hbuf, const float* tm1,
    short* huhi, short* hulo,
    const unsigned short* lo0_t, short* xhhi, short* xhlo)
{
  const int tid = threadIdx.x;
  const int blk = blockIdx.x;
  const int n0 = (blk & 15) * 32;
  const int m0 = (blk >> 4) * 32;
  const int w = tid >> 6, l = tid & 63;
  const int sr = tid >> 3;               // tile row 0..31
  const int scs = (tid & 7) ^ (sr & 7);  // pre-swizzled source chunk

  f32x4 acc = {0.f, 0.f, 0.f, 0.f};

  auto stage = [&](int kt) {
    const int buf = kt % 3;
    const int blkk = kt >> 3;
    const int kk = (kt & 7) << 6;
    const short* Asrc = (blkk == 1) ? hlo : hhi;
    const int boff = kk + ((blkk == 2) ? 512 : 0);
    gload16c(Asrc + (size_t)(m0 + sr) * H_ + kk + scs * 8, (char*)As[buf] + w * 1024);
    gload16(Wds + (size_t)(n0 + sr) * 1024 + boff + scs * 8, (char*)Bs[buf] + w * 1024);
  };

  stage(0); stage(1);

  const int wm = w & 1, wn = w >> 1;
  const int ar = wm * 16 + (l & 15);
  const int br = wn * 16 + (l & 15);
  const int koff = (l >> 4) * 16;
  const int aswz = (ar & 7) << 4;
  const int bswz = (br & 7) << 4;

  for (int kt = 0; kt < 24; ++kt) {
    const int buf = kt % 3;
    if (kt < 23) { asm volatile("s_waitcnt vmcnt(2)" ::: "memory"); }
    else         { asm volatile("s_waitcnt vmcnt(0)" ::: "memory"); }
    __syncthreads();
    if (kt + 2 < 24) stage(kt + 2);
#pragma unroll
    for (int k2 = 0; k2 < 2; ++k2) {
      s16x8 af = *(const s16x8*)((char*)As[buf] + ((ar * 128 + k2 * 64 + koff) ^ aswz));
      s16x8 bf = *(const s16x8*)((char*)Bs[buf] + ((br * 128 + k2 * 64 + koff) ^ bswz));
      acc = __builtin_amdgcn_mfma_f32_16x16x32_bf16(af, bf, acc, 0, 0, 0);
    }
  }

  const int n_abs = n0 + wn * 16 + (l & 15);
  const int mbase = m0 + wm * 16 + (l >> 4) * 4;
  const float bv = bd[n_abs];
#pragma unroll
  for (int r = 0; r < 4; ++r) {
    const int m_abs = mbase + r;
    float cst = tanhf(acc[r] + bv);
    float hu = ldf_coh(hbuf + (size_t)m_abs * H_ + n_abs) + tm1[m_abs] * cst;
    unsigned short hi = f2bf(hu);
    sth_coh(huhi + (size_t)m_abs * H_ + n_abs, hi);
    sth_coh(hulo + (size_t)m_abs * H_ + n_abs, f2bf(hu - bf2f(hi)));
    if (CVT) {
      float xv = h2f(ldh_coh(lo0_t + (size_t)m_abs * NSEQH + n_abs));
      unsigned short xh = f2bf(xv);
      sth_coh(xhhi + (size_t)m_abs * H_ + n_abs, xh);
      sth_coh(xhlo + (size_t)m_abs * H_ + n_abs, f2bf(xv - bf2f(xh)));
    }
  }
}

// ---------------------------------------------------------------------------
// G2: z = [x,h_upd] @ W.T + b -> cell update. 64m x (16j x 4 gates)/block,
// blk->(j=blk&31, m=blk>>5) [blk%8 = j%8 -> W slice stays on one XCD].
// ---------------------------------------------------------------------------
template<int K, int TPB, int KPS, int XK, int XSTR, bool STORE_LO0>
__device__ __forceinline__ void g2_phase(
    char (*As)[8192], char (*Bs)[8192],
    const short* xhi, const short* xlo,
    const short* huhi, const short* hulo,
    const short* Wsp, const float* bias,
    float* cbuf, float* hbuf, short* hhi, short* hlo,
    unsigned short* lo0_t)
{
  constexpr int NT = 3 * K / 64;
  const int tid = threadIdx.x;
  const int blk = blockIdx.x;
  const int j0 = (blk & 31) * 16;
  const int m0 = (blk >> 5) * 64;
  const int w = tid >> 6, l = tid & 63;

  f32x4 acc[4];
#pragma unroll
  for (int i = 0; i < 4; ++i) acc[i] = (f32x4){0.f, 0.f, 0.f, 0.f};

  auto stage = [&](int kt) {
    const int buf = kt % 3;
    const int blkk = kt / TPB;
    const int kk = (kt - blkk * TPB) << 6;
    const bool lo_a = (blkk == 1);
    const int boff = kk + ((blkk == 2) ? K : 0);
#pragma unroll
    for (int j = 0; j < 2; ++j) {
      const int s = tid + j * 256;
      const int r = s >> 3;
      const int cs = (s & 7) ^ (r & 7);
      const short* asrc; size_t aoff;
      if (kk < XK) { asrc = lo_a ? xlo : xhi;   aoff = (size_t)(m0 + r) * XSTR + kk + cs * 8; }
      else         { asrc = lo_a ? hulo : huhi; aoff = (size_t)(m0 + r) * H_ + (kk - XK) + cs * 8; }
      gload16c(asrc + aoff, (char*)As[buf] + j * 4096 + w * 1024);
      const int src_n = (r >> 4) * H_ + j0 + (r & 15);
      gload16(Wsp + (size_t)src_n * KPS + boff + cs * 8,
              (char*)Bs[buf] + j * 4096 + w * 1024);
    }
  };

  stage(0); stage(1);

  const int ar = w * 16 + (l & 15);
  const int koff = (l >> 4) * 16;
  const int aswz = (ar & 7) << 4;

  for (int kt = 0; kt < NT; ++kt) {
    const int buf = kt % 3;
    if (kt < NT - 1) { asm volatile("s_waitcnt vmcnt(4)" ::: "memory"); }
    else             { asm volatile("s_waitcnt vmcnt(0)" ::: "memory"); }
    __syncthreads();
    if (kt + 2 < NT) stage(kt + 2);
#pragma unroll
    for (int k2 = 0; k2 < 2; ++k2) {
      s16x8 af = *(const s16x8*)((char*)As[buf] + ((ar * 128 + k2 * 64 + koff) ^ aswz));
#pragma unroll
      for (int nf = 0; nf < 4; ++nf) {
        const int br = nf * 16 + (l & 15);
        s16x8 bf = *(const s16x8*)((char*)Bs[buf] + ((br * 128 + k2 * 64 + koff) ^ ((br & 7) << 4)));
        acc[nf] = __builtin_amdgcn_mfma_f32_16x16x32_bf16(af, bf, acc[nf], 0, 0, 0);
      }
    }
  }

  const int j_abs = j0 + (l & 15);
  const float bi  = bias[j_abs];
  const float bfv = bias[H_ + j_abs];
  const float bo  = bias[2 * H_ + j_abs];
  const float bg  = bias[3 * H_ + j_abs];
  const int mbase = m0 + w * 16 + (l >> 4) * 4;
#pragma unroll
  for (int r = 0; r < 4; ++r) {
    const int m_abs = mbase + r;
    float zi = acc[0][r] + bi;
    float zf = acc[1][r] + bfv;
    float zo = acc[2][r] + bo;
    float zg = acc[3][r] + bg;
    float co = ldf_coh(cbuf + (size_t)m_abs * H_ + j_abs);
    float cn = sigf(zf) * co + sigf(zi) * tanhf(zg);
    float hn = sigf(zo) * tanhf(cn);
    stf_coh(cbuf + (size_t)m_abs * H_ + j_abs, cn);
    stf_coh(hbuf + (size_t)m_abs * H_ + j_abs, hn);
    unsigned short hi = f2bf(hn);
    sth_coh(hhi + (size_t)m_abs * H_ + j_abs, hi);
    sth_coh(hlo + (size_t)m_abs * H_ + j_abs, f2bf(hn - bf2f(hi)));
    if (STORE_LO0)
      sth_coh((short*)(lo0_t + (size_t)m_abs * NSEQH + j_abs), f2h(hn));
  }
}

// ---------------------------------------------------------------------------
// Persistent kernel
// ---------------------------------------------------------------------------
__global__ __launch_bounds__(256, 1) void persist(
    const float* inputs,
    const float* W0, const float* b0, const float* Wd0, const float* bd0,
    const float* W1, const float* b1, const float* Wd1, const float* bd1,
    float* out,
    unsigned short* lo0, short* xinhi, short* xinlo,
    float* hbuf, float* cbuf,
    short* hhi, short* hlo, short* huhi, short* hulo,
    short* xhhi, short* xhlo,
    float* Tm1T, short* Wd0s, short* Wd1s, short* W0s, short* W1s,
    unsigned* bar)
{
  __shared__ __align__(16) char As[3][8192];
  __shared__ __align__(16) char Bs[3][8192];
  const int gtid = blockIdx.x * 256 + threadIdx.x;
  int nb = 0;

  // ---- prologue (plain stores; published by the one heavy barrier) ----
  auto dosplit = [&](const float* W, short* Ws, int N, int Ksrc, int Kpad, int pad_at) {
    const int total = N * Kpad;
    for (int idx = gtid; idx < total; idx += NTHR) {
      int n = idx / Kpad, c = idx - n * Kpad;
      int sc = c;
      if (pad_at >= 0) { if (c == pad_at) sc = -1; else if (c > pad_at) sc = c - 1; }
      float v = 0.f;
      if (sc >= 0 && sc < Ksrc) v = W[(size_t)n * Ksrc + sc];
      unsigned short hi = f2bf(v);
      unsigned short lo = f2bf(v - bf2f(hi));
      size_t base = (size_t)n * (2 * Kpad);
      Ws[base + c]        = (short)hi;
      Ws[base + Kpad + c] = (short)lo;
    }
  };
  dosplit(Wd0, Wd0s, 512, 512, 512, -1);
  dosplit(Wd1, Wd1s, 512, 512, 512, -1);
  dosplit(W0, W0s, 2048, 575, 576, 63);
  dosplit(W1, W1s, 2048, 1024, 1024, -1);
  for (int idx = gtid; idx < B_ * SEQ_ * 64; idx += NTHR) {
    float v = inputs[idx];
    unsigned short hi = f2bf(v);
    xinhi[idx] = (short)hi;
    xinlo[idx] = (short)f2bf(v - bf2f(hi));
  }
  for (int idx = gtid; idx < B_ * SEQ_; idx += NTHR) {
    int b = idx / SEQ_, t = idx - b * SEQ_;
    float dt = inputs[(size_t)b * (SEQ_ * 64) + t * 64 + 63];
    Tm1T[t * B_ + b] = 1.0f / logf(dt + 2.7183f) - 1.0f;
  }
  for (int idx = gtid; idx < B_ * H_; idx += NTHR) {
    hbuf[idx] = 0.f; cbuf[idx] = 0.f; hhi[idx] = 0; hlo[idx] = 0;
  }
  gbar_heavy(bar);

  for (int layer = 0; layer < 2; ++layer) {
    if (layer == 1) {
      for (int idx = gtid; idx < B_ * H_; idx += NTHR) {
        stf_coh(hbuf + idx, 0.f); stf_coh(cbuf + idx, 0.f);
        sth_coh(hhi + idx, 0);    sth_coh(hlo + idx, 0);
      }
      lbar(bar, nb);
    }
    for (int s = 0; s < SEQ_; ++s) {
      const int torig = SEQ_ - 1 - s;
      if (layer == 0) {
        g1_phase<false>(As, Bs, hhi, hlo, Wd0s, bd0, hbuf,
                        Tm1T + (size_t)torig * B_, huhi, hulo,
                        nullptr, nullptr, nullptr);
        lbar(bar, nb);
        g2_phase<576, 9, 1152, 64, SEQ_ * 64, true>(
            As, Bs, xinhi + (size_t)torig * 64, xinlo + (size_t)torig * 64,
            huhi, hulo, W0s, b0, cbuf, hbuf, hhi, hlo,
            lo0 + (size_t)s * H_);
        lbar(bar, nb);
      } else {
        g1_phase<true>(As, Bs, hhi, hlo, Wd1s, bd1, hbuf,
                       Tm1T + (size_t)torig * B_, huhi, hulo,
                       lo0 + (size_t)torig * H_, xhhi, xhlo);
        lbar(bar, nb);
        g2_phase<1024, 16, 2048, 512, H_, false>(
            As, Bs, xhhi, xhlo, huhi, hulo, W1s, b1,
            cbuf, hbuf, hhi, hlo, nullptr);
        lbar(bar, nb);
      }
    }
  }

  for (int idx = gtid; idx < B_ * H_; idx += NTHR)
    out[idx] = ldf_coh(hbuf + idx);
}

extern "C" void kernel_launch(void* const* d_in, const int* in_sizes, int n_in,
                              void* d_out, int out_size, void* d_ws, size_t ws_size,
                              hipStream_t stream) {
  const float* inputs = (const float*)d_in[0];
  const float* W0  = (const float*)d_in[1];
  const float* b0  = (const float*)d_in[2];
  const float* Wd0 = (const float*)d_in[3];
  const float* bd0 = (const float*)d_in[4];
  const float* W1  = (const float*)d_in[5];
  const float* b1  = (const float*)d_in[6];
  const float* Wd1 = (const float*)d_in[7];
  const float* bd1 = (const float*)d_in[8];

  char* ws = (char*)d_ws;
  size_t off = 0;
  auto alloc = [&](size_t bytes) -> char* {
    char* p = ws + off;
    off += (bytes + 1023) & ~(size_t)1023;
    return p;
  };
  unsigned* bar = (unsigned*)alloc(2048);
  unsigned short* lo0 = (unsigned short*)alloc((size_t)B_ * SEQ_ * H_ * 2); // fp16
  short* xinhi = (short*)alloc((size_t)B_ * SEQ_ * 64 * 2);
  short* xinlo = (short*)alloc((size_t)B_ * SEQ_ * 64 * 2);
  float* hbuf  = (float*)alloc((size_t)B_ * H_ * 4);
  float* cbuf  = (float*)alloc((size_t)B_ * H_ * 4);
  short* hhi   = (short*)alloc((size_t)B_ * H_ * 2);
  short* hlo   = (short*)alloc((size_t)B_ * H_ * 2);
  short* huhi  = (short*)alloc((size_t)B_ * H_ * 2);
  short* hulo  = (short*)alloc((size_t)B_ * H_ * 2);
  short* xhhi  = (short*)alloc((size_t)B_ * H_ * 2);
  short* xhlo  = (short*)alloc((size_t)B_ * H_ * 2);
  float* Tm1T  = (float*)alloc((size_t)SEQ_ * B_ * 4);
  short* Wd0s  = (short*)alloc((size_t)512 * 1024 * 2);
  short* Wd1s  = (short*)alloc((size_t)512 * 1024 * 2);
  short* W0s   = (short*)alloc((size_t)2048 * 1152 * 2);
  short* W1s   = (short*)alloc((size_t)2048 * 2048 * 2);

  if (off > ws_size) {
    fill_kernel<<<(out_size + 255) / 256, 256, 0, stream>>>(
        (float*)d_out, out_size, (float)(ws_size >> 20));
    return;
  }

  hipMemsetAsync(bar, 0, 2048, stream);
  persist<<<NBLK, 256, 0, stream>>>(
      inputs, W0, b0, Wd0, bd0, W1, b1, Wd1, bd1,
      (float*)d_out,
      lo0, xinhi, xinlo, hbuf, cbuf,
      hhi, hlo, huhi, hulo, xhhi, xhlo,
      Tm1T, Wd0s, Wd1s, W0s, W1s, bar);
}

// Round 7
// 22047.943 us; speedup vs baseline: 3.0933x; 1.9355x over previous
//
#include <hip/hip_runtime.h>
#include <stdint.h>

#define B_    512
#define SEQ_  256
#define H_    512
#define NSEQH (SEQ_ * H_)
#define NBLK  256
#define NTHR  (NBLK * 256)

using f32x4 = __attribute__((ext_vector_type(4))) float;
using s16x8 = __attribute__((ext_vector_type(8))) short;

#define WAITVM(N) asm volatile("s_waitcnt vmcnt(" #N ")" ::: "memory")
#define SBAR()    asm volatile("s_barrier" ::: "memory")

__device__ inline unsigned short f2bf(float f) {
  union { float f; uint32_t u; } x; x.f = f;
  uint32_t u = x.u;
  uint32_t r = u + 0x7fffu + ((u >> 16) & 1u);
  return (unsigned short)(r >> 16);
}
__device__ inline float bf2f(unsigned short h) {
  union { float f; uint32_t u; } x; x.u = ((uint32_t)h) << 16;
  return x.f;
}
__device__ inline float h2f(unsigned short u) {
  _Float16 h; __builtin_memcpy(&h, &u, 2); return (float)h;
}
__device__ inline unsigned short f2h(float f) {
  _Float16 h = (_Float16)f; unsigned short u; __builtin_memcpy(&u, &h, 2); return u;
}
__device__ inline float sigf(float x) { return 1.0f / (1.0f + expf(-x)); }

// async global->LDS, cached (read-only data: weights, static inputs)
__device__ inline void gload16(const void* g, void* l) {
  __builtin_amdgcn_global_load_lds(
      (const __attribute__((address_space(1))) void*)g,
      (__attribute__((address_space(3))) void*)l, 16, 0, 0);
}
// async global->LDS, coherent (sc0|sc1): bypasses stale per-XCD L2.
__device__ inline void gload16c(const void* g, void* l) {
  __builtin_amdgcn_global_load_lds(
      (const __attribute__((address_space(1))) void*)g,
      (__attribute__((address_space(3))) void*)l, 16, 0, 17);
}

// coherent scalar helpers (compiler-managed sc0sc1 + waitcnt)
__device__ __forceinline__ float ldf_coh(const float* p) {
  return __hip_atomic_load(p, __ATOMIC_RELAXED, __HIP_MEMORY_SCOPE_SYSTEM);
}
__device__ __forceinline__ unsigned short ldh_coh(const unsigned short* p) {
  return __hip_atomic_load(p, __ATOMIC_RELAXED, __HIP_MEMORY_SCOPE_SYSTEM);
}
__device__ __forceinline__ void stf_coh(float* p, float v) {
  __hip_atomic_store(p, v, __ATOMIC_RELAXED, __HIP_MEMORY_SCOPE_SYSTEM);
}
__device__ __forceinline__ void sth_coh(short* p, unsigned short v) {
  __hip_atomic_store((unsigned short*)p, v, __ATOMIC_RELAXED, __HIP_MEMORY_SCOPE_SYSTEM);
}

// heavy barrier (agent acq_rel -> L2 writeback+invalidate). Once, post-prologue.
__device__ __forceinline__ void gbar_heavy(unsigned* bar) {
  __syncthreads();
  if (threadIdx.x == 0) {
    unsigned g = __hip_atomic_load(bar + 1, __ATOMIC_RELAXED, __HIP_MEMORY_SCOPE_AGENT);
    unsigned a = __hip_atomic_fetch_add(bar, 1u, __ATOMIC_ACQ_REL, __HIP_MEMORY_SCOPE_AGENT);
    if (a == (unsigned)(NBLK - 1)) {
      __hip_atomic_store(bar, 0u, __ATOMIC_RELAXED, __HIP_MEMORY_SCOPE_AGENT);
      __hip_atomic_store(bar + 1, g + 1u, __ATOMIC_RELEASE, __HIP_MEMORY_SCOPE_AGENT);
    } else {
      while (__hip_atomic_load(bar + 1, __ATOMIC_ACQUIRE, __HIP_MEMORY_SCOPE_AGENT) == g)
        __builtin_amdgcn_s_sleep(2);
    }
  }
  __syncthreads();
}

// light barrier: no cache maintenance; sc0sc1 data drained by __syncthreads.
__device__ __forceinline__ void lbar(unsigned* bar, int& nb) {
  __syncthreads();
  ++nb;
  if (threadIdx.x == 0) {
    unsigned* leaf = bar + 32 + (blockIdx.x >> 5) * 32;
    unsigned* root = bar + 8;
    unsigned old = __hip_atomic_fetch_add(leaf, 1u, __ATOMIC_RELAXED, __HIP_MEMORY_SCOPE_SYSTEM);
    if ((old & 31u) == 31u)
      __hip_atomic_fetch_add(root, 1u, __ATOMIC_RELAXED, __HIP_MEMORY_SCOPE_SYSTEM);
    const unsigned target = (unsigned)(8 * nb);
    while ((int)(__hip_atomic_load(root, __ATOMIC_RELAXED, __HIP_MEMORY_SCOPE_SYSTEM) - target) < 0)
      __builtin_amdgcn_s_sleep(1);
  }
  __syncthreads();
}

__global__ void fill_kernel(float* __restrict__ out, int n, float v) {
  int i = blockIdx.x * blockDim.x + threadIdx.x;
  if (i < n) out[i] = v;
}

// ---------------------------------------------------------------------------
// G1: h_upd = h + Tm1*tanh(h @ Wd.T + bd). 32x32 tile, blk->(n=blk&15,m=blk>>4).
// K'=3*512 = 24 tiles. Raw s_barrier + counted vmcnt, 3-ahead / 4 buffers.
// A (h splits, step-varying): coherent DMA. B (weights): cached DMA.
// ---------------------------------------------------------------------------
template<bool CVT>
__device__ __forceinline__ void g1_phase(
    char (*As)[8192], char (*Bs)[8192],
    const short* hhi, const short* hlo,
    const short* Wds, const float* bd,
    const float* hbuf, const float* tm1,
    short* huhi, short* hulo,
    const unsigned short* lo0_t, short* xhhi, short* xhlo)
{
  const int tid = threadIdx.x;
  const int blk = blockIdx.x;
  const int n0 = (blk & 15) * 32;
  const int m0 = (blk >> 4) * 32;
  const int w = tid >> 6, l = tid & 63;
  const int sr = tid >> 3;               // tile row 0..31
  const int scs = (tid & 7) ^ (sr & 7);  // pre-swizzled source chunk

  auto stage = [&](int kt) {
    const int buf = kt & 3;
    const int blkk = kt >> 3;
    const int kk = (kt & 7) << 6;
    const short* Asrc = (blkk == 1) ? hlo : hhi;
    const int boff = kk + ((blkk == 2) ? 512 : 0);
    gload16c(Asrc + (size_t)(m0 + sr) * H_ + kk + scs * 8, (char*)As[buf] + w * 1024);
    gload16(Wds + (size_t)(n0 + sr) * 1024 + boff + scs * 8, (char*)Bs[buf] + w * 1024);
  };

  stage(0); stage(1); stage(2);

  const int wm = w & 1, wn = w >> 1;
  const int ar = wm * 16 + (l & 15);
  const int br = wn * 16 + (l & 15);
  const int koff = (l >> 4) * 16;
  const int aswz = (ar & 7) << 4;
  const int bswz = (br & 7) << 4;

  f32x4 acc = {0.f, 0.f, 0.f, 0.f};

  for (int kt = 0; kt < 24; ++kt) {
    if (kt + 2 < 24)      WAITVM(4);   // tile kt's 2 loads done
    else if (kt + 1 < 24) WAITVM(2);
    else                  WAITVM(0);
    SBAR();                             // all waves' tile-kt DMA landed
    if (kt + 3 < 24) stage(kt + 3);     // overwrites buf consumed at kt-1
    const int buf = kt & 3;
#pragma unroll
    for (int k2 = 0; k2 < 2; ++k2) {
      s16x8 af = *(const s16x8*)((char*)As[buf] + ((ar * 128 + k2 * 64 + koff) ^ aswz));
      s16x8 bf = *(const s16x8*)((char*)Bs[buf] + ((br * 128 + k2 * 64 + koff) ^ bswz));
      acc = __builtin_amdgcn_mfma_f32_16x16x32_bf16(af, bf, acc, 0, 0, 0);
    }
  }

  const int n_abs = n0 + wn * 16 + (l & 15);
  const int mbase = m0 + wm * 16 + (l >> 4) * 4;
  const float bv = bd[n_abs];
#pragma unroll
  for (int r = 0; r < 4; ++r) {
    const int m_abs = mbase + r;
    float cst = tanhf(acc[r] + bv);
    float hu = ldf_coh(hbuf + (size_t)m_abs * H_ + n_abs) + tm1[m_abs] * cst;
    unsigned short hi = f2bf(hu);
    sth_coh(huhi + (size_t)m_abs * H_ + n_abs, hi);
    sth_coh(hulo + (size_t)m_abs * H_ + n_abs, f2bf(hu - bf2f(hi)));
    if (CVT) {
      float xv = h2f(ldh_coh(lo0_t + (size_t)m_abs * NSEQH + n_abs));
      unsigned short xh = f2bf(xv);
      sth_coh(xhhi + (size_t)m_abs * H_ + n_abs, xh);
      sth_coh(xhlo + (size_t)m_abs * H_ + n_abs, f2bf(xv - bf2f(xh)));
    }
  }
}

// ---------------------------------------------------------------------------
// G2: z = [x,h_upd] @ W.T + b -> cell update. 64m x (16j x 4 gates)/block,
// blk->(j=blk&31, m=blk>>5). c-state lives in REGISTERS (cv), block-private.
// XCOH: x-part coherent (L1: xh changes per step) vs cached (L0: static).
// ---------------------------------------------------------------------------
template<int K, int TPB, int KPS, int XK, int XSTR, bool STORE_LO0, bool XCOH>
__device__ __forceinline__ void g2_phase(
    char (*As)[8192], char (*Bs)[8192],
    const short* xhi, const short* xlo,
    const short* huhi, const short* hulo,
    const short* Wsp, const float* bias,
    f32x4& cv, float* hbuf, short* hhi, short* hlo,
    unsigned short* lo0_t)
{
  constexpr int NT = 3 * K / 64;
  const int tid = threadIdx.x;
  const int blk = blockIdx.x;
  const int j0 = (blk & 31) * 16;
  const int m0 = (blk >> 5) * 64;
  const int w = tid >> 6, l = tid & 63;

  auto stage = [&](int kt) {
    const int buf = kt & 3;
    const int blkk = kt / TPB;
    const int kk = (kt - blkk * TPB) << 6;
    const bool lo_a = (blkk == 1);
    const int boff = kk + ((blkk == 2) ? K : 0);
#pragma unroll
    for (int j = 0; j < 2; ++j) {
      const int s = tid + j * 256;
      const int r = s >> 3;
      const int cs = (s & 7) ^ (r & 7);
      if (kk < XK) {
        const short* asrc = lo_a ? xlo : xhi;
        const size_t aoff = (size_t)(m0 + r) * XSTR + kk + cs * 8;
        if (XCOH) gload16c(asrc + aoff, (char*)As[buf] + j * 4096 + w * 1024);
        else      gload16 (asrc + aoff, (char*)As[buf] + j * 4096 + w * 1024);
      } else {
        const short* asrc = lo_a ? hulo : huhi;
        gload16c(asrc + (size_t)(m0 + r) * H_ + (kk - XK) + cs * 8,
                 (char*)As[buf] + j * 4096 + w * 1024);
      }
      const int src_n = (r >> 4) * H_ + j0 + (r & 15);
      gload16(Wsp + (size_t)src_n * KPS + boff + cs * 8,
              (char*)Bs[buf] + j * 4096 + w * 1024);
    }
  };

  stage(0); stage(1); stage(2);

  const int ar = w * 16 + (l & 15);
  const int koff = (l >> 4) * 16;
  const int aswz = (ar & 7) << 4;

  f32x4 acc[4];
#pragma unroll
  for (int i = 0; i < 4; ++i) acc[i] = (f32x4){0.f, 0.f, 0.f, 0.f};

  for (int kt = 0; kt < NT; ++kt) {
    if (kt + 2 < NT)      WAITVM(8);   // tile kt's 4 loads done
    else if (kt + 1 < NT) WAITVM(4);
    else                  WAITVM(0);
    SBAR();
    if (kt + 3 < NT) stage(kt + 3);
    const int buf = kt & 3;
#pragma unroll
    for (int k2 = 0; k2 < 2; ++k2) {
      s16x8 af = *(const s16x8*)((char*)As[buf] + ((ar * 128 + k2 * 64 + koff) ^ aswz));
#pragma unroll
      for (int nf = 0; nf < 4; ++nf) {
        const int br = nf * 16 + (l & 15);
        s16x8 bf = *(const s16x8*)((char*)Bs[buf] + ((br * 128 + k2 * 64 + koff) ^ ((br & 7) << 4)));
        acc[nf] = __builtin_amdgcn_mfma_f32_16x16x32_bf16(af, bf, acc[nf], 0, 0, 0);
      }
    }
  }

  const int j_abs = j0 + (l & 15);
  const float bi  = bias[j_abs];
  const float bfv = bias[H_ + j_abs];
  const float bo  = bias[2 * H_ + j_abs];
  const float bg  = bias[3 * H_ + j_abs];
  const int mbase = m0 + w * 16 + (l >> 4) * 4;
#pragma unroll
  for (int r = 0; r < 4; ++r) {
    const int m_abs = mbase + r;
    float zi = acc[0][r] + bi;
    float zf = acc[1][r] + bfv;
    float zo = acc[2][r] + bo;
    float zg = acc[3][r] + bg;
    float cn = sigf(zf) * cv[r] + sigf(zi) * tanhf(zg);
    float hn = sigf(zo) * tanhf(cn);
    cv[r] = cn;                                   // c stays in registers
    stf_coh(hbuf + (size_t)m_abs * H_ + j_abs, hn);
    unsigned short hi = f2bf(hn);
    sth_coh(hhi + (size_t)m_abs * H_ + j_abs, hi);
    sth_coh(hlo + (size_t)m_abs * H_ + j_abs, f2bf(hn - bf2f(hi)));
    if (STORE_LO0)
      sth_coh((short*)(lo0_t + (size_t)m_abs * NSEQH + j_abs), f2h(hn));
  }
}

// ---------------------------------------------------------------------------
// Persistent kernel
// ---------------------------------------------------------------------------
__global__ __launch_bounds__(256, 1) void persist(
    const float* inputs,
    const float* W0, const float* b0, const float* Wd0, const float* bd0,
    const float* W1, const float* b1, const float* Wd1, const float* bd1,
    float* out,
    unsigned short* lo0, short* xinhi, short* xinlo,
    float* hbuf,
    short* hhi, short* hlo, short* huhi, short* hulo,
    short* xhhi, short* xhlo,
    float* Tm1T, short* Wd0s, short* Wd1s, short* W0s, short* W1s,
    unsigned* bar)
{
  __shared__ __align__(16) char As[4][8192];
  __shared__ __align__(16) char Bs[4][8192];
  const int gtid = blockIdx.x * 256 + threadIdx.x;
  int nb = 0;

  auto dosplit = [&](const float* W, short* Ws, int N, int Ksrc, int Kpad, int pad_at) {
    const int total = N * Kpad;
    for (int idx = gtid; idx < total; idx += NTHR) {
      int n = idx / Kpad, c = idx - n * Kpad;
      int sc = c;
      if (pad_at >= 0) { if (c == pad_at) sc = -1; else if (c > pad_at) sc = c - 1; }
      float v = 0.f;
      if (sc >= 0 && sc < Ksrc) v = W[(size_t)n * Ksrc + sc];
      unsigned short hi = f2bf(v);
      unsigned short lo = f2bf(v - bf2f(hi));
      size_t base = (size_t)n * (2 * Kpad);
      Ws[base + c]        = (short)hi;
      Ws[base + Kpad + c] = (short)lo;
    }
  };
  dosplit(Wd0, Wd0s, 512, 512, 512, -1);
  dosplit(Wd1, Wd1s, 512, 512, 512, -1);
  dosplit(W0, W0s, 2048, 575, 576, 63);
  dosplit(W1, W1s, 2048, 1024, 1024, -1);
  for (int idx = gtid; idx < B_ * SEQ_ * 64; idx += NTHR) {
    float v = inputs[idx];
    unsigned short hi = f2bf(v);
    xinhi[idx] = (short)hi;
    xinlo[idx] = (short)f2bf(v - bf2f(hi));
  }
  for (int idx = gtid; idx < B_ * SEQ_; idx += NTHR) {
    int b = idx / SEQ_, t = idx - b * SEQ_;
    float dt = inputs[(size_t)b * (SEQ_ * 64) + t * 64 + 63];
    Tm1T[t * B_ + b] = 1.0f / logf(dt + 2.7183f) - 1.0f;
  }
  for (int idx = gtid; idx < B_ * H_; idx += NTHR) {
    hbuf[idx] = 0.f; hhi[idx] = 0; hlo[idx] = 0;
  }
  gbar_heavy(bar);

  for (int layer = 0; layer < 2; ++layer) {
    f32x4 cv = {0.f, 0.f, 0.f, 0.f};     // register c-state, block-private
    if (layer == 1) {
      for (int idx = gtid; idx < B_ * H_; idx += NTHR) {
        stf_coh(hbuf + idx, 0.f);
        sth_coh(hhi + idx, 0); sth_coh(hlo + idx, 0);
      }
      lbar(bar, nb);
    }
    for (int s = 0; s < SEQ_; ++s) {
      const int torig = SEQ_ - 1 - s;
      if (layer == 0) {
        g1_phase<false>(As, Bs, hhi, hlo, Wd0s, bd0, hbuf,
                        Tm1T + (size_t)torig * B_, huhi, hulo,
                        nullptr, nullptr, nullptr);
        lbar(bar, nb);
        g2_phase<576, 9, 1152, 64, SEQ_ * 64, true, false>(
            As, Bs, xinhi + (size_t)torig * 64, xinlo + (size_t)torig * 64,
            huhi, hulo, W0s, b0, cv, hbuf, hhi, hlo,
            lo0 + (size_t)s * H_);
        lbar(bar, nb);
      } else {
        g1_phase<true>(As, Bs, hhi, hlo, Wd1s, bd1, hbuf,
                       Tm1T + (size_t)torig * B_, huhi, hulo,
                       lo0 + (size_t)torig * H_, xhhi, xhlo);
        lbar(bar, nb);
        g2_phase<1024, 16, 2048, 512, H_, false, true>(
            As, Bs, xhhi, xhlo, huhi, hulo, W1s, b1,
            cv, hbuf, hhi, hlo, nullptr);
        lbar(bar, nb);
      }
    }
  }

  for (int idx = gtid; idx < B_ * H_; idx += NTHR)
    out[idx] = ldf_coh(hbuf + idx);
}

extern "C" void kernel_launch(void* const* d_in, const int* in_sizes, int n_in,
                              void* d_out, int out_size, void* d_ws, size_t ws_size,
                              hipStream_t stream) {
  const float* inputs = (const float*)d_in[0];
  const float* W0  = (const float*)d_in[1];
  const float* b0  = (const float*)d_in[2];
  const float* Wd0 = (const float*)d_in[3];
  const float* bd0 = (const float*)d_in[4];
  const float* W1  = (const float*)d_in[5];
  const float* b1  = (const float*)d_in[6];
  const float* Wd1 = (const float*)d_in[7];
  const float* bd1 = (const float*)d_in[8];

  char* ws = (char*)d_ws;
  size_t off = 0;
  auto alloc = [&](size_t bytes) -> char* {
    char* p = ws + off;
    off += (bytes + 1023) & ~(size_t)1023;
    return p;
  };
  unsigned* bar = (unsigned*)alloc(2048);
  unsigned short* lo0 = (unsigned short*)alloc((size_t)B_ * SEQ_ * H_ * 2); // fp16
  short* xinhi = (short*)alloc((size_t)B_ * SEQ_ * 64 * 2);
  short* xinlo = (short*)alloc((size_t)B_ * SEQ_ * 64 * 2);
  float* hbuf  = (float*)alloc((size_t)B_ * H_ * 4);
  short* hhi   = (short*)alloc((size_t)B_ * H_ * 2);
  short* hlo   = (short*)alloc((size_t)B_ * H_ * 2);
  short* huhi  = (short*)alloc((size_t)B_ * H_ * 2);
  short* hulo  = (short*)alloc((size_t)B_ * H_ * 2);
  short* xhhi  = (short*)alloc((size_t)B_ * H_ * 2);
  short* xhlo  = (short*)alloc((size_t)B_ * H_ * 2);
  float* Tm1T  = (float*)alloc((size_t)SEQ_ * B_ * 4);
  short* Wd0s  = (short*)alloc((size_t)512 * 1024 * 2);
  short* Wd1s  = (short*)alloc((size_t)512 * 1024 * 2);
  short* W0s   = (short*)alloc((size_t)2048 * 1152 * 2);
  short* W1s   = (short*)alloc((size_t)2048 * 2048 * 2);

  if (off > ws_size) {
    fill_kernel<<<(out_size + 255) / 256, 256, 0, stream>>>(
        (float*)d_out, out_size, (float)(ws_size >> 20));
    return;
  }

  hipMemsetAsync(bar, 0, 2048, stream);
  persist<<<NBLK, 256, 0, stream>>>(
      inputs, W0, b0, Wd0, bd0, W1, b1, Wd1, bd1,
      (float*)d_out,
      lo0, xinhi, xinlo, hbuf,
      hhi, hlo, huhi, hulo, xhhi, xhlo,
      Tm1T, Wd0s, Wd1s, W0s, W1s, bar);
}

// Round 8
// 21986.397 us; speedup vs baseline: 3.1020x; 1.0028x over previous
//
#include <hip/hip_runtime.h>
#include <stdint.h>

#define B_    512
#define SEQ_  256
#define H_    512
#define NSEQH (SEQ_ * H_)
#define NBLK  256
#define NTHR  (NBLK * 256)

using f32x4 = __attribute__((ext_vector_type(4))) float;
using s16x8 = __attribute__((ext_vector_type(8))) short;

#define WAITVM(N) asm volatile("s_waitcnt vmcnt(" #N ")" ::: "memory")
#define SBAR()    asm volatile("s_barrier" ::: "memory")

__device__ inline unsigned short f2bf(float f) {
  union { float f; uint32_t u; } x; x.f = f;
  uint32_t u = x.u;
  uint32_t r = u + 0x7fffu + ((u >> 16) & 1u);
  return (unsigned short)(r >> 16);
}
__device__ inline float bf2f(unsigned short h) {
  union { float f; uint32_t u; } x; x.u = ((uint32_t)h) << 16;
  return x.f;
}
__device__ inline float h2f(unsigned short u) {
  _Float16 h; __builtin_memcpy(&h, &u, 2); return (float)h;
}
__device__ inline unsigned short f2h(float f) {
  _Float16 h = (_Float16)f; unsigned short u; __builtin_memcpy(&u, &h, 2); return u;
}
__device__ inline float sigf(float x) { return 1.0f / (1.0f + expf(-x)); }

// async global->LDS, cached (read-only data: weights, static inputs)
__device__ inline void gload16(const void* g, void* l) {
  __builtin_amdgcn_global_load_lds(
      (const __attribute__((address_space(1))) void*)g,
      (__attribute__((address_space(3))) void*)l, 16, 0, 0);
}
// async global->LDS, coherent (sc0|sc1): bypasses stale per-XCD L2.
__device__ inline void gload16c(const void* g, void* l) {
  __builtin_amdgcn_global_load_lds(
      (const __attribute__((address_space(1))) void*)g,
      (__attribute__((address_space(3))) void*)l, 16, 0, 17);
}

// coherent scalar helpers (compiler-managed sc0sc1 + waitcnt)
__device__ __forceinline__ float ldf_coh(const float* p) {
  return __hip_atomic_load(p, __ATOMIC_RELAXED, __HIP_MEMORY_SCOPE_SYSTEM);
}
__device__ __forceinline__ unsigned short ldh_coh(const unsigned short* p) {
  return __hip_atomic_load(p, __ATOMIC_RELAXED, __HIP_MEMORY_SCOPE_SYSTEM);
}
__device__ __forceinline__ void stf_coh(float* p, float v) {
  __hip_atomic_store(p, v, __ATOMIC_RELAXED, __HIP_MEMORY_SCOPE_SYSTEM);
}
__device__ __forceinline__ void sth_coh(short* p, unsigned short v) {
  __hip_atomic_store((unsigned short*)p, v, __ATOMIC_RELAXED, __HIP_MEMORY_SCOPE_SYSTEM);
}

// heavy barrier (agent acq_rel -> L2 writeback+invalidate). Once, post-prologue.
__device__ __forceinline__ void gbar_heavy(unsigned* bar) {
  __syncthreads();
  if (threadIdx.x == 0) {
    unsigned g = __hip_atomic_load(bar + 1, __ATOMIC_RELAXED, __HIP_MEMORY_SCOPE_AGENT);
    unsigned a = __hip_atomic_fetch_add(bar, 1u, __ATOMIC_ACQ_REL, __HIP_MEMORY_SCOPE_AGENT);
    if (a == (unsigned)(NBLK - 1)) {
      __hip_atomic_store(bar, 0u, __ATOMIC_RELAXED, __HIP_MEMORY_SCOPE_AGENT);
      __hip_atomic_store(bar + 1, g + 1u, __ATOMIC_RELEASE, __HIP_MEMORY_SCOPE_AGENT);
    } else {
      while (__hip_atomic_load(bar + 1, __ATOMIC_ACQUIRE, __HIP_MEMORY_SCOPE_AGENT) == g)
        __builtin_amdgcn_s_sleep(2);
    }
  }
  __syncthreads();
}

// light barrier: no cache maintenance; sc0sc1 data drained by __syncthreads.
__device__ __forceinline__ void lbar(unsigned* bar, int& nb) {
  __syncthreads();
  ++nb;
  if (threadIdx.x == 0) {
    unsigned* leaf = bar + 32 + (blockIdx.x >> 5) * 32;
    unsigned* root = bar + 8;
    unsigned old = __hip_atomic_fetch_add(leaf, 1u, __ATOMIC_RELAXED, __HIP_MEMORY_SCOPE_SYSTEM);
    if ((old & 31u) == 31u)
      __hip_atomic_fetch_add(root, 1u, __ATOMIC_RELAXED, __HIP_MEMORY_SCOPE_SYSTEM);
    const unsigned target = (unsigned)(8 * nb);
    while ((int)(__hip_atomic_load(root, __ATOMIC_RELAXED, __HIP_MEMORY_SCOPE_SYSTEM) - target) < 0)
      __builtin_amdgcn_s_sleep(1);
  }
  __syncthreads();
}

__global__ void fill_kernel(float* __restrict__ out, int n, float v) {
  int i = blockIdx.x * blockDim.x + threadIdx.x;
  if (i < n) out[i] = v;
}

// Deterministic XCD-aware slot assignment: block b on XCD x with rank r
// (arrival order by block id among same-XCD blocks) takes slot x*32+r if
// r<32; spill blocks fill unclaimed slots in deterministic order. All
// blocks compute identical mappings from the shared xcdmap[].
__device__ int compute_slot(const int* xcdmap, int myblk) {
  int cnt[8] = {0,0,0,0,0,0,0,0};
  int rank = -1;
  for (int b = 0; b < NBLK; ++b) {
    int x = xcdmap[b] & 7;
    int r = cnt[x]++;
    if (b == myblk) rank = r;
  }
  int myx = xcdmap[myblk] & 7;
  if (rank < 32) return myx * 32 + rank;
  int spill_idx = 0;
  {
    int c2[8] = {0,0,0,0,0,0,0,0};
    for (int b = 0; b < myblk; ++b) {
      int x = xcdmap[b] & 7;
      if (c2[x]++ >= 32) ++spill_idx;
    }
  }
  int k = 0;
  for (int g = 0; g < 8; ++g) {
    int filled = cnt[g] < 32 ? cnt[g] : 32;
    for (int rr = filled; rr < 32; ++rr) {
      if (k == spill_idx) return g * 32 + rr;
      ++k;
    }
  }
  return 0;
}

// ---------------------------------------------------------------------------
// G1: h_upd = h + Tm1*tanh(h @ Wd.T + bd). 32x32 tile; (m0,n0) from XCD-aware
// slot (same-n blocks physically share an XCD -> Wd slice L2-resident).
// ---------------------------------------------------------------------------
template<bool CVT>
__device__ __forceinline__ void g1_phase(
    char (*As)[8192], char (*Bs)[8192], int m0, int n0,
    const short* hhi, const short* hlo,
    const short* Wds, const float* bd,
    const float* hbuf, const float* tm1,
    short* huhi, short* hulo,
    const unsigned short* lo0_t, short* xhhi, short* xhlo)
{
  const int tid = threadIdx.x;
  const int w = tid >> 6, l = tid & 63;
  const int sr = tid >> 3;               // tile row 0..31
  const int scs = (tid & 7) ^ (sr & 7);  // pre-swizzled source chunk

  auto stage = [&](int kt) {
    const int buf = kt & 3;
    const int blkk = kt >> 3;
    const int kk = (kt & 7) << 6;
    const short* Asrc = (blkk == 1) ? hlo : hhi;
    const int boff = kk + ((blkk == 2) ? 512 : 0);
    gload16c(Asrc + (size_t)(m0 + sr) * H_ + kk + scs * 8, (char*)As[buf] + w * 1024);
    gload16(Wds + (size_t)(n0 + sr) * 1024 + boff + scs * 8, (char*)Bs[buf] + w * 1024);
  };

  stage(0); stage(1); stage(2);

  const int wm = w & 1, wn = w >> 1;
  const int ar = wm * 16 + (l & 15);
  const int br = wn * 16 + (l & 15);
  const int koff = (l >> 4) * 16;
  const int aswz = (ar & 7) << 4;
  const int bswz = (br & 7) << 4;

  f32x4 acc = {0.f, 0.f, 0.f, 0.f};

  for (int kt = 0; kt < 24; ++kt) {
    if (kt + 2 < 24)      WAITVM(4);
    else if (kt + 1 < 24) WAITVM(2);
    else                  WAITVM(0);
    SBAR();
    if (kt + 3 < 24) stage(kt + 3);
    const int buf = kt & 3;
#pragma unroll
    for (int k2 = 0; k2 < 2; ++k2) {
      s16x8 af = *(const s16x8*)((char*)As[buf] + ((ar * 128 + k2 * 64 + koff) ^ aswz));
      s16x8 bf = *(const s16x8*)((char*)Bs[buf] + ((br * 128 + k2 * 64 + koff) ^ bswz));
      acc = __builtin_amdgcn_mfma_f32_16x16x32_bf16(af, bf, acc, 0, 0, 0);
    }
  }

  const int n_abs = n0 + wn * 16 + (l & 15);
  const int mbase = m0 + wm * 16 + (l >> 4) * 4;
  const float bv = bd[n_abs];
#pragma unroll
  for (int r = 0; r < 4; ++r) {
    const int m_abs = mbase + r;
    float cst = tanhf(acc[r] + bv);
    float hu = ldf_coh(hbuf + (size_t)m_abs * H_ + n_abs) + tm1[m_abs] * cst;
    unsigned short hi = f2bf(hu);
    sth_coh(huhi + (size_t)m_abs * H_ + n_abs, hi);
    sth_coh(hulo + (size_t)m_abs * H_ + n_abs, f2bf(hu - bf2f(hi)));
    if (CVT) {
      float xv = h2f(ldh_coh(lo0_t + (size_t)m_abs * NSEQH + n_abs));
      unsigned short xh = f2bf(xv);
      sth_coh(xhhi + (size_t)m_abs * H_ + n_abs, xh);
      sth_coh(xhlo + (size_t)m_abs * H_ + n_abs, f2bf(xv - bf2f(xh)));
    }
  }
}

// ---------------------------------------------------------------------------
// G2: z = [x,h_upd] @ W.T + b -> cell update. (m0,j0) from XCD-aware slot
// (same-j blocks physically share an XCD -> W slice L2-resident).
// ---------------------------------------------------------------------------
template<int K, int TPB, int KPS, int XK, int XSTR, bool STORE_LO0, bool XCOH>
__device__ __forceinline__ void g2_phase(
    char (*As)[8192], char (*Bs)[8192], int m0, int j0,
    const short* xhi, const short* xlo,
    const short* huhi, const short* hulo,
    const short* Wsp, const float* bias,
    f32x4& cv, float* hbuf, short* hhi, short* hlo,
    unsigned short* lo0_t)
{
  constexpr int NT = 3 * K / 64;
  const int tid = threadIdx.x;
  const int w = tid >> 6, l = tid & 63;

  auto stage = [&](int kt) {
    const int buf = kt & 3;
    const int blkk = kt / TPB;
    const int kk = (kt - blkk * TPB) << 6;
    const bool lo_a = (blkk == 1);
    const int boff = kk + ((blkk == 2) ? K : 0);
#pragma unroll
    for (int j = 0; j < 2; ++j) {
      const int s = tid + j * 256;
      const int r = s >> 3;
      const int cs = (s & 7) ^ (r & 7);
      if (kk < XK) {
        const short* asrc = lo_a ? xlo : xhi;
        const size_t aoff = (size_t)(m0 + r) * XSTR + kk + cs * 8;
        if (XCOH) gload16c(asrc + aoff, (char*)As[buf] + j * 4096 + w * 1024);
        else      gload16 (asrc + aoff, (char*)As[buf] + j * 4096 + w * 1024);
      } else {
        const short* asrc = lo_a ? hulo : huhi;
        gload16c(asrc + (size_t)(m0 + r) * H_ + (kk - XK) + cs * 8,
                 (char*)As[buf] + j * 4096 + w * 1024);
      }
      const int src_n = (r >> 4) * H_ + j0 + (r & 15);
      gload16(Wsp + (size_t)src_n * KPS + boff + cs * 8,
              (char*)Bs[buf] + j * 4096 + w * 1024);
    }
  };

  stage(0); stage(1); stage(2);

  const int ar = w * 16 + (l & 15);
  const int koff = (l >> 4) * 16;
  const int aswz = (ar & 7) << 4;

  f32x4 acc[4];
#pragma unroll
  for (int i = 0; i < 4; ++i) acc[i] = (f32x4){0.f, 0.f, 0.f, 0.f};

  for (int kt = 0; kt < NT; ++kt) {
    if (kt + 2 < NT)      WAITVM(8);
    else if (kt + 1 < NT) WAITVM(4);
    else                  WAITVM(0);
    SBAR();
    if (kt + 3 < NT) stage(kt + 3);
    const int buf = kt & 3;
#pragma unroll
    for (int k2 = 0; k2 < 2; ++k2) {
      s16x8 af = *(const s16x8*)((char*)As[buf] + ((ar * 128 + k2 * 64 + koff) ^ aswz));
#pragma unroll
      for (int nf = 0; nf < 4; ++nf) {
        const int br = nf * 16 + (l & 15);
        s16x8 bf = *(const s16x8*)((char*)Bs[buf] + ((br * 128 + k2 * 64 + koff) ^ ((br & 7) << 4)));
        acc[nf] = __builtin_amdgcn_mfma_f32_16x16x32_bf16(af, bf, acc[nf], 0, 0, 0);
      }
    }
  }

  const int j_abs = j0 + (l & 15);
  const float bi  = bias[j_abs];
  const float bfv = bias[H_ + j_abs];
  const float bo  = bias[2 * H_ + j_abs];
  const float bg  = bias[3 * H_ + j_abs];
  const int mbase = m0 + w * 16 + (l >> 4) * 4;
#pragma unroll
  for (int r = 0; r < 4; ++r) {
    const int m_abs = mbase + r;
    float zi = acc[0][r] + bi;
    float zf = acc[1][r] + bfv;
    float zo = acc[2][r] + bo;
    float zg = acc[3][r] + bg;
    float cn = sigf(zf) * cv[r] + sigf(zi) * tanhf(zg);
    float hn = sigf(zo) * tanhf(cn);
    cv[r] = cn;
    stf_coh(hbuf + (size_t)m_abs * H_ + j_abs, hn);
    unsigned short hi = f2bf(hn);
    sth_coh(hhi + (size_t)m_abs * H_ + j_abs, hi);
    sth_coh(hlo + (size_t)m_abs * H_ + j_abs, f2bf(hn - bf2f(hi)));
    if (STORE_LO0)
      sth_coh((short*)(lo0_t + (size_t)m_abs * NSEQH + j_abs), f2h(hn));
  }
}

// ---------------------------------------------------------------------------
// Persistent kernel
// ---------------------------------------------------------------------------
__global__ __launch_bounds__(256, 1) void persist(
    const float* inputs,
    const float* W0, const float* b0, const float* Wd0, const float* bd0,
    const float* W1, const float* b1, const float* Wd1, const float* bd1,
    float* out,
    unsigned short* lo0, short* xinhi, short* xinlo,
    float* hbuf,
    short* hhi, short* hlo, short* huhi, short* hulo,
    short* xhhi, short* xhlo,
    float* Tm1T, short* Wd0s, short* Wd1s, short* W0s, short* W1s,
    unsigned* bar, int* xcdmap)
{
  __shared__ __align__(16) char As[4][8192];
  __shared__ __align__(16) char Bs[4][8192];
  const int gtid = blockIdx.x * 256 + threadIdx.x;
  int nb = 0;

  // publish this block's physical XCD id
  if (threadIdx.x == 0) {
    unsigned xcc;
    asm volatile("s_getreg_b32 %0, hwreg(20, 0, 32)" : "=s"(xcc)); // HW_REG_XCC_ID
    xcdmap[blockIdx.x] = (int)(xcc & 7u);
  }

  auto dosplit = [&](const float* W, short* Ws, int N, int Ksrc, int Kpad, int pad_at) {
    const int total = N * Kpad;
    for (int idx = gtid; idx < total; idx += NTHR) {
      int n = idx / Kpad, c = idx - n * Kpad;
      int sc = c;
      if (pad_at >= 0) { if (c == pad_at) sc = -1; else if (c > pad_at) sc = c - 1; }
      float v = 0.f;
      if (sc >= 0 && sc < Ksrc) v = W[(size_t)n * Ksrc + sc];
      unsigned short hi = f2bf(v);
      unsigned short lo = f2bf(v - bf2f(hi));
      size_t base = (size_t)n * (2 * Kpad);
      Ws[base + c]        = (short)hi;
      Ws[base + Kpad + c] = (short)lo;
    }
  };
  dosplit(Wd0, Wd0s, 512, 512, 512, -1);
  dosplit(Wd1, Wd1s, 512, 512, 512, -1);
  dosplit(W0, W0s, 2048, 575, 576, 63);
  dosplit(W1, W1s, 2048, 1024, 1024, -1);
  for (int idx = gtid; idx < B_ * SEQ_ * 64; idx += NTHR) {
    float v = inputs[idx];
    unsigned short hi = f2bf(v);
    xinhi[idx] = (short)hi;
    xinlo[idx] = (short)f2bf(v - bf2f(hi));
  }
  for (int idx = gtid; idx < B_ * SEQ_; idx += NTHR) {
    int b = idx / SEQ_, t = idx - b * SEQ_;
    float dt = inputs[(size_t)b * (SEQ_ * 64) + t * 64 + 63];
    Tm1T[t * B_ + b] = 1.0f / logf(dt + 2.7183f) - 1.0f;
  }
  for (int idx = gtid; idx < B_ * H_; idx += NTHR) {
    hbuf[idx] = 0.f; hhi[idx] = 0; hlo[idx] = 0;
  }
  gbar_heavy(bar);

  // XCD-aware work slots (all threads compute identical mapping)
  const int myw = compute_slot(xcdmap, blockIdx.x);
  const int wg = myw >> 5, rr = myw & 31;
  const int g1_n0 = (wg * 2 + (rr & 1)) * 32;   // 16 n-slices, 2 per XCD
  const int g1_m0 = (rr >> 1) * 32;             // 16 m-tiles per n
  const int g2_j0 = (wg * 4 + (rr & 3)) * 16;   // 32 j-slices, 4 per XCD
  const int g2_m0 = (rr >> 2) * 64;             // 8 m-tiles per j

  for (int layer = 0; layer < 2; ++layer) {
    f32x4 cv = {0.f, 0.f, 0.f, 0.f};
    if (layer == 1) {
      for (int idx = gtid; idx < B_ * H_; idx += NTHR) {
        stf_coh(hbuf + idx, 0.f);
        sth_coh(hhi + idx, 0); sth_coh(hlo + idx, 0);
      }
      lbar(bar, nb);
    }
    for (int s = 0; s < SEQ_; ++s) {
      const int torig = SEQ_ - 1 - s;
      if (layer == 0) {
        g1_phase<false>(As, Bs, g1_m0, g1_n0, hhi, hlo, Wd0s, bd0, hbuf,
                        Tm1T + (size_t)torig * B_, huhi, hulo,
                        nullptr, nullptr, nullptr);
        lbar(bar, nb);
        g2_phase<576, 9, 1152, 64, SEQ_ * 64, true, false>(
            As, Bs, g2_m0, g2_j0,
            xinhi + (size_t)torig * 64, xinlo + (size_t)torig * 64,
            huhi, hulo, W0s, b0, cv, hbuf, hhi, hlo,
            lo0 + (size_t)s * H_);
        lbar(bar, nb);
      } else {
        g1_phase<true>(As, Bs, g1_m0, g1_n0, hhi, hlo, Wd1s, bd1, hbuf,
                       Tm1T + (size_t)torig * B_, huhi, hulo,
                       lo0 + (size_t)torig * H_, xhhi, xhlo);
        lbar(bar, nb);
        g2_phase<1024, 16, 2048, 512, H_, false, true>(
            As, Bs, g2_m0, g2_j0,
            xhhi, xhlo, huhi, hulo, W1s, b1,
            cv, hbuf, hhi, hlo, nullptr);
        lbar(bar, nb);
      }
    }
  }

  for (int idx = gtid; idx < B_ * H_; idx += NTHR)
    out[idx] = ldf_coh(hbuf + idx);
}

extern "C" void kernel_launch(void* const* d_in, const int* in_sizes, int n_in,
                              void* d_out, int out_size, void* d_ws, size_t ws_size,
                              hipStream_t stream) {
  const float* inputs = (const float*)d_in[0];
  const float* W0  = (const float*)d_in[1];
  const float* b0  = (const float*)d_in[2];
  const float* Wd0 = (const float*)d_in[3];
  const float* bd0 = (const float*)d_in[4];
  const float* W1  = (const float*)d_in[5];
  const float* b1  = (const float*)d_in[6];
  const float* Wd1 = (const float*)d_in[7];
  const float* bd1 = (const float*)d_in[8];

  char* ws = (char*)d_ws;
  size_t off = 0;
  auto alloc = [&](size_t bytes) -> char* {
    char* p = ws + off;
    off += (bytes + 1023) & ~(size_t)1023;
    return p;
  };
  unsigned* bar = (unsigned*)alloc(2048);
  int* xcdmap = (int*)alloc(NBLK * 4);
  unsigned short* lo0 = (unsigned short*)alloc((size_t)B_ * SEQ_ * H_ * 2); // fp16
  short* xinhi = (short*)alloc((size_t)B_ * SEQ_ * 64 * 2);
  short* xinlo = (short*)alloc((size_t)B_ * SEQ_ * 64 * 2);
  float* hbuf  = (float*)alloc((size_t)B_ * H_ * 4);
  short* hhi   = (short*)alloc((size_t)B_ * H_ * 2);
  short* hlo   = (short*)alloc((size_t)B_ * H_ * 2);
  short* huhi  = (short*)alloc((size_t)B_ * H_ * 2);
  short* hulo  = (short*)alloc((size_t)B_ * H_ * 2);
  short* xhhi  = (short*)alloc((size_t)B_ * H_ * 2);
  short* xhlo  = (short*)alloc((size_t)B_ * H_ * 2);
  float* Tm1T  = (float*)alloc((size_t)SEQ_ * B_ * 4);
  short* Wd0s  = (short*)alloc((size_t)512 * 1024 * 2);
  short* Wd1s  = (short*)alloc((size_t)512 * 1024 * 2);
  short* W0s   = (short*)alloc((size_t)2048 * 1152 * 2);
  short* W1s   = (short*)alloc((size_t)2048 * 2048 * 2);

  if (off > ws_size) {
    fill_kernel<<<(out_size + 255) / 256, 256, 0, stream>>>(
        (float*)d_out, out_size, (float)(ws_size >> 20));
    return;
  }

  hipMemsetAsync(bar, 0, 2048, stream);
  persist<<<NBLK, 256, 0, stream>>>(
      inputs, W0, b0, Wd0, bd0, W1, b1, Wd1, bd1,
      (float*)d_out,
      lo0, xinhi, xinlo, hbuf,
      hhi, hlo, huhi, hulo, xhhi, xhlo,
      Tm1T, Wd0s, Wd1s, W0s, W1s, bar, xcdmap);
}

// Round 9
// 10310.226 us; speedup vs baseline: 6.6149x; 2.1325x over previous
//
#include <hip/hip_runtime.h>
#include <stdint.h>

#define B_    512
#define SEQ_  256
#define H_    512
#define NSEQH (SEQ_ * H_)
#define NBLK  256
#define NTHR  (NBLK * 256)

using f32x4 = __attribute__((ext_vector_type(4))) float;
using s16x8 = __attribute__((ext_vector_type(8))) short;

#define WAITVM(N) asm volatile("s_waitcnt vmcnt(" #N ")" ::: "memory")
#define SBAR()    asm volatile("s_barrier" ::: "memory")

__device__ inline unsigned short f2bf(float f) {
  union { float f; uint32_t u; } x; x.f = f;
  uint32_t u = x.u;
  uint32_t r = u + 0x7fffu + ((u >> 16) & 1u);
  return (unsigned short)(r >> 16);
}
__device__ inline float bf2f(unsigned short h) {
  union { float f; uint32_t u; } x; x.u = ((uint32_t)h) << 16;
  return x.f;
}
__device__ inline float h2f(unsigned short u) {
  _Float16 h; __builtin_memcpy(&h, &u, 2); return (float)h;
}
__device__ inline unsigned short f2h(float f) {
  _Float16 h = (_Float16)f; unsigned short u; __builtin_memcpy(&u, &h, 2); return u;
}
__device__ inline float sigf(float x) { return 1.0f / (1.0f + expf(-x)); }

// async global->LDS, cached (read-only data: weights, static inputs)
__device__ inline void gload16(const void* g, void* l) {
  __builtin_amdgcn_global_load_lds(
      (const __attribute__((address_space(1))) void*)g,
      (__attribute__((address_space(3))) void*)l, 16, 0, 0);
}
// async global->LDS, coherent (sc0|sc1): reads the coherent point.
__device__ inline void gload16c(const void* g, void* l) {
  __builtin_amdgcn_global_load_lds(
      (const __attribute__((address_space(1))) void*)g,
      (__attribute__((address_space(3))) void*)l, 16, 0, 17);
}

// coherent scalar helpers (compiler-managed sc0sc1 + waitcnt)
__device__ __forceinline__ unsigned short ldh_coh(const unsigned short* p) {
  return __hip_atomic_load(p, __ATOMIC_RELAXED, __HIP_MEMORY_SCOPE_SYSTEM);
}
__device__ __forceinline__ void sth_coh(short* p, unsigned short v) {
  __hip_atomic_store((unsigned short*)p, v, __ATOMIC_RELAXED, __HIP_MEMORY_SCOPE_SYSTEM);
}

// heavy barrier (agent acq_rel -> L2 writeback+invalidate). Once, post-prologue.
__device__ __forceinline__ void gbar_heavy(unsigned* bar) {
  __syncthreads();
  if (threadIdx.x == 0) {
    unsigned g = __hip_atomic_load(bar + 1, __ATOMIC_RELAXED, __HIP_MEMORY_SCOPE_AGENT);
    unsigned a = __hip_atomic_fetch_add(bar, 1u, __ATOMIC_ACQ_REL, __HIP_MEMORY_SCOPE_AGENT);
    if (a == (unsigned)(NBLK - 1)) {
      __hip_atomic_store(bar, 0u, __ATOMIC_RELAXED, __HIP_MEMORY_SCOPE_AGENT);
      __hip_atomic_store(bar + 1, g + 1u, __ATOMIC_RELEASE, __HIP_MEMORY_SCOPE_AGENT);
    } else {
      while (__hip_atomic_load(bar + 1, __ATOMIC_ACQUIRE, __HIP_MEMORY_SCOPE_AGENT) == g)
        __builtin_amdgcn_s_sleep(2);
    }
  }
  __syncthreads();
}

// light barrier: no cache maintenance; sc0sc1 data drained by __syncthreads.
__device__ __forceinline__ void lbar(unsigned* bar, int& nb) {
  __syncthreads();
  ++nb;
  if (threadIdx.x == 0) {
    unsigned* leaf = bar + 32 + (blockIdx.x >> 5) * 32;
    unsigned* root = bar + 8;
    unsigned old = __hip_atomic_fetch_add(leaf, 1u, __ATOMIC_RELAXED, __HIP_MEMORY_SCOPE_SYSTEM);
    if ((old & 31u) == 31u)
      __hip_atomic_fetch_add(root, 1u, __ATOMIC_RELAXED, __HIP_MEMORY_SCOPE_SYSTEM);
    const unsigned target = (unsigned)(8 * nb);
    while ((int)(__hip_atomic_load(root, __ATOMIC_RELAXED, __HIP_MEMORY_SCOPE_SYSTEM) - target) < 0)
      __builtin_amdgcn_s_sleep(1);
  }
  __syncthreads();
}

__global__ void fill_kernel(float* __restrict__ out, int n, float v) {
  int i = blockIdx.x * blockDim.x + threadIdx.x;
  if (i < n) out[i] = v;
}

// deterministic XCD-aware slot assignment (same as R8)
__device__ int compute_slot(const int* xcdmap, int myblk) {
  int cnt[8] = {0,0,0,0,0,0,0,0};
  int rank = -1;
  for (int b = 0; b < NBLK; ++b) {
    int x = xcdmap[b] & 7;
    int r = cnt[x]++;
    if (b == myblk) rank = r;
  }
  int myx = xcdmap[myblk] & 7;
  if (rank < 32) return myx * 32 + rank;
  int spill_idx = 0;
  {
    int c2[8] = {0,0,0,0,0,0,0,0};
    for (int b = 0; b < myblk; ++b) {
      int x = xcdmap[b] & 7;
      if (c2[x]++ >= 32) ++spill_idx;
    }
  }
  int k = 0;
  for (int g = 0; g < 8; ++g) {
    int filled = cnt[g] < 32 ? cnt[g] : 32;
    for (int rr = filled; rr < 32; ++rr) {
      if (k == spill_idx) return g * 32 + rr;
      ++k;
    }
  }
  return 0;
}

// ---------------------------------------------------------------------------
// G1: h_upd = h + Tm1*tanh(h @ Wd.T + bd). 32x32 tile. Paired-reuse K-loop:
// per kk stage {A_hi, A_lo, W_hi, W_lo} (16 KB set), 3 products (6 MFMA).
// 8 iterations, 4 LDS sets, single barrier/iter, 3-deep prefetch.
// ---------------------------------------------------------------------------
template<bool CVT>
__device__ __forceinline__ void g1_phase(
    char* LDS, int m0, int n0,
    const short* hhi, const short* hlo,
    const short* Wds, const float* bd, const float* tm1,
    short* huhi, short* hulo,
    const unsigned short* lo0_t, short* xhhi, short* xhlo)
{
  const int tid = threadIdx.x;
  const int w = tid >> 6, l = tid & 63;
  const int sr = tid >> 3;               // tile row 0..31
  const int scs = (tid & 7) ^ (sr & 7);  // pre-swizzled source chunk

  auto stage = [&](int kt) {
    char* base = LDS + (kt & 3) * 16384;
    const int kb = kt << 6;
    const size_t aoff = (size_t)(m0 + sr) * H_ + kb + scs * 8;
    gload16c(hhi + aoff, base + w * 1024);
    gload16c(hlo + aoff, base + 4096 + w * 1024);
    const size_t boff = (size_t)(n0 + sr) * 1024 + kb + scs * 8;
    gload16(Wds + boff,       base + 8192  + w * 1024);
    gload16(Wds + boff + 512, base + 12288 + w * 1024);
  };

  stage(0); stage(1); stage(2);

  const int wm = w & 1, wn = w >> 1;
  const int ar = wm * 16 + (l & 15);
  const int br = wn * 16 + (l & 15);
  const int koff = (l >> 4) * 16;
  const int aswz = (ar & 7) << 4;
  const int bswz = (br & 7) << 4;

  f32x4 acc = {0.f, 0.f, 0.f, 0.f};

  for (int kt = 0; kt < 8; ++kt) {
    if (kt < 6)       WAITVM(8);
    else if (kt == 6) WAITVM(4);
    else              WAITVM(0);
    SBAR();
    if (kt + 3 < 8) stage(kt + 3);
    char* base = LDS + (kt & 3) * 16384;
#pragma unroll
    for (int k2 = 0; k2 < 2; ++k2) {
      const int ao = (ar * 128 + k2 * 64 + koff) ^ aswz;
      const int bo = (br * 128 + k2 * 64 + koff) ^ bswz;
      s16x8 a_hi = *(const s16x8*)(base + ao);
      s16x8 a_lo = *(const s16x8*)(base + 4096 + ao);
      s16x8 b_hi = *(const s16x8*)(base + 8192 + bo);
      s16x8 b_lo = *(const s16x8*)(base + 12288 + bo);
      acc = __builtin_amdgcn_mfma_f32_16x16x32_bf16(a_hi, b_hi, acc, 0, 0, 0);
      acc = __builtin_amdgcn_mfma_f32_16x16x32_bf16(a_lo, b_hi, acc, 0, 0, 0);
      acc = __builtin_amdgcn_mfma_f32_16x16x32_bf16(a_hi, b_lo, acc, 0, 0, 0);
    }
  }

  const int n_abs = n0 + wn * 16 + (l & 15);
  const int mbase = m0 + wm * 16 + (l >> 4) * 4;
  const float bv = bd[n_abs];
#pragma unroll
  for (int r = 0; r < 4; ++r) {
    const int m_abs = mbase + r;
    const size_t off = (size_t)m_abs * H_ + n_abs;
    float cst = tanhf(acc[r] + bv);
    float hv = bf2f(ldh_coh((const unsigned short*)hhi + off)) +
               bf2f(ldh_coh((const unsigned short*)hlo + off));
    float hu = hv + tm1[m_abs] * cst;
    unsigned short hi = f2bf(hu);
    sth_coh(huhi + off, hi);
    sth_coh(hulo + off, f2bf(hu - bf2f(hi)));
    if (CVT) {
      float xv = h2f(ldh_coh(lo0_t + (size_t)m_abs * NSEQH + n_abs));
      unsigned short xh = f2bf(xv);
      sth_coh(xhhi + off, xh);
      sth_coh(xhlo + off, f2bf(xv - bf2f(xh)));
    }
  }
}

// ---------------------------------------------------------------------------
// G2: z = [x,h_upd] @ W.T + b -> cell update. 64m x (16j x 4 gates)/block.
// Paired-reuse K-loop: per kk stage {A_hi, A_lo, W_hi, W_lo} (32 KB set),
// 3 products x 4 nf x 2 k2 = 24 MFMA. NT=K/64 iters, 2 LDS sets,
// two s_barriers/iter. c-state in registers.
// ---------------------------------------------------------------------------
template<int K, int XK, int XSTR, bool STORE_LO0, bool XCOH>
__device__ __forceinline__ void g2_phase(
    char* LDS, int m0, int j0,
    const short* xhi, const short* xlo,
    const short* huhi, const short* hulo,
    const short* Wsp, const float* bias,
    f32x4& cv, short* hhi, short* hlo,
    unsigned short* lo0_t)
{
  constexpr int NT = K / 64;
  constexpr int KPS = 2 * K;
  const int tid = threadIdx.x;
  const int w = tid >> 6, l = tid & 63;

  auto stage = [&](int kt) {
    char* base = LDS + (kt & 1) * 32768;
    const int kb = kt << 6;
#pragma unroll
    for (int j = 0; j < 2; ++j) {
      const int s = tid + j * 256;
      const int r = s >> 3;
      const int cs = (s & 7) ^ (r & 7);
      const int dst = j * 4096 + w * 1024;
      if (kb < XK) {
        const size_t aoff = (size_t)(m0 + r) * XSTR + kb + cs * 8;
        if (XCOH) { gload16c(xhi + aoff, base + dst); gload16c(xlo + aoff, base + 8192 + dst); }
        else      { gload16 (xhi + aoff, base + dst); gload16 (xlo + aoff, base + 8192 + dst); }
      } else {
        const size_t aoff = (size_t)(m0 + r) * H_ + (kb - XK) + cs * 8;
        gload16c(huhi + aoff, base + dst);
        gload16c(hulo + aoff, base + 8192 + dst);
      }
      const int src_n = (r >> 4) * H_ + j0 + (r & 15);
      const size_t boff = (size_t)src_n * KPS + kb + cs * 8;
      gload16(Wsp + boff,     base + 16384 + dst);
      gload16(Wsp + boff + K, base + 24576 + dst);
    }
  };

  stage(0); stage(1);

  const int ar = w * 16 + (l & 15);
  const int koff = (l >> 4) * 16;
  const int aswz = (ar & 7) << 4;

  f32x4 acc[4];
#pragma unroll
  for (int i = 0; i < 4; ++i) acc[i] = (f32x4){0.f, 0.f, 0.f, 0.f};

  for (int kt = 0; kt < NT; ++kt) {
    if (kt + 1 < NT) WAITVM(8);
    else             WAITVM(0);
    SBAR();
    char* base = LDS + (kt & 1) * 32768;
#pragma unroll
    for (int k2 = 0; k2 < 2; ++k2) {
      const int ao = (ar * 128 + k2 * 64 + koff) ^ aswz;
      s16x8 a_hi = *(const s16x8*)(base + ao);
      s16x8 a_lo = *(const s16x8*)(base + 8192 + ao);
#pragma unroll
      for (int nf = 0; nf < 4; ++nf) {
        const int br = nf * 16 + (l & 15);
        const int bo = (br * 128 + k2 * 64 + koff) ^ ((br & 7) << 4);
        s16x8 b_hi = *(const s16x8*)(base + 16384 + bo);
        s16x8 b_lo = *(const s16x8*)(base + 24576 + bo);
        acc[nf] = __builtin_amdgcn_mfma_f32_16x16x32_bf16(a_hi, b_hi, acc[nf], 0, 0, 0);
        acc[nf] = __builtin_amdgcn_mfma_f32_16x16x32_bf16(a_lo, b_hi, acc[nf], 0, 0, 0);
        acc[nf] = __builtin_amdgcn_mfma_f32_16x16x32_bf16(a_hi, b_lo, acc[nf], 0, 0, 0);
      }
    }
    SBAR();
    if (kt + 2 < NT) stage(kt + 2);
  }

  const int j_abs = j0 + (l & 15);
  const float bi  = bias[j_abs];
  const float bfv = bias[H_ + j_abs];
  const float bo  = bias[2 * H_ + j_abs];
  const float bg  = bias[3 * H_ + j_abs];
  const int mbase = m0 + w * 16 + (l >> 4) * 4;
#pragma unroll
  for (int r = 0; r < 4; ++r) {
    const int m_abs = mbase + r;
    float zi = acc[0][r] + bi;
    float zf = acc[1][r] + bfv;
    float zo = acc[2][r] + bo;
    float zg = acc[3][r] + bg;
    float cn = sigf(zf) * cv[r] + sigf(zi) * tanhf(zg);
    float hn = sigf(zo) * tanhf(cn);
    cv[r] = cn;
    const size_t off = (size_t)m_abs * H_ + j_abs;
    unsigned short hi = f2bf(hn);
    sth_coh(hhi + off, hi);
    sth_coh(hlo + off, f2bf(hn - bf2f(hi)));
    if (STORE_LO0)
      sth_coh((short*)(lo0_t + (size_t)m_abs * NSEQH + j_abs), f2h(hn));
  }
}

// ---------------------------------------------------------------------------
// Persistent kernel
// ---------------------------------------------------------------------------
__global__ __launch_bounds__(256, 1) void persist(
    const float* inputs,
    const float* W0, const float* b0, const float* Wd0, const float* bd0,
    const float* W1, const float* b1, const float* Wd1, const float* bd1,
    float* out,
    unsigned short* lo0, short* xinhi, short* xinlo,
    short* hhi, short* hlo, short* huhi, short* hulo,
    short* xhhi, short* xhlo,
    float* Tm1T, short* Wd0s, short* Wd1s, short* W0s, short* W1s,
    unsigned* bar, int* xcdmap)
{
  __shared__ __align__(16) char LDS[65536];
  const int gtid = blockIdx.x * 256 + threadIdx.x;
  int nb = 0;

  if (threadIdx.x == 0) {
    unsigned xcc;
    asm volatile("s_getreg_b32 %0, hwreg(20, 0, 32)" : "=s"(xcc)); // HW_REG_XCC_ID
    xcdmap[blockIdx.x] = (int)(xcc & 7u);
  }

  auto dosplit = [&](const float* W, short* Ws, int N, int Ksrc, int Kpad, int pad_at) {
    const int total = N * Kpad;
    for (int idx = gtid; idx < total; idx += NTHR) {
      int n = idx / Kpad, c = idx - n * Kpad;
      int sc = c;
      if (pad_at >= 0) { if (c == pad_at) sc = -1; else if (c > pad_at) sc = c - 1; }
      float v = 0.f;
      if (sc >= 0 && sc < Ksrc) v = W[(size_t)n * Ksrc + sc];
      unsigned short hi = f2bf(v);
      unsigned short lo = f2bf(v - bf2f(hi));
      size_t base = (size_t)n * (2 * Kpad);
      Ws[base + c]        = (short)hi;
      Ws[base + Kpad + c] = (short)lo;
    }
  };
  dosplit(Wd0, Wd0s, 512, 512, 512, -1);
  dosplit(Wd1, Wd1s, 512, 512, 512, -1);
  dosplit(W0, W0s, 2048, 575, 576, 63);
  dosplit(W1, W1s, 2048, 1024, 1024, -1);
  for (int idx = gtid; idx < B_ * SEQ_ * 64; idx += NTHR) {
    float v = inputs[idx];
    unsigned short hi = f2bf(v);
    xinhi[idx] = (short)hi;
    xinlo[idx] = (short)f2bf(v - bf2f(hi));
  }
  for (int idx = gtid; idx < B_ * SEQ_; idx += NTHR) {
    int b = idx / SEQ_, t = idx - b * SEQ_;
    float dt = inputs[(size_t)b * (SEQ_ * 64) + t * 64 + 63];
    Tm1T[t * B_ + b] = 1.0f / logf(dt + 2.7183f) - 1.0f;
  }
  for (int idx = gtid; idx < B_ * H_; idx += NTHR) {
    hhi[idx] = 0; hlo[idx] = 0;
  }
  gbar_heavy(bar);

  const int myw = compute_slot(xcdmap, blockIdx.x);
  const int wg = myw >> 5, rr = myw & 31;
  const int g1_n0 = (wg * 2 + (rr & 1)) * 32;   // 16 n-slices, 2 per XCD
  const int g1_m0 = (rr >> 1) * 32;             // 16 m-tiles per n
  const int g2_j0 = (wg * 4 + (rr & 3)) * 16;   // 32 j-slices, 4 per XCD
  const int g2_m0 = (rr >> 2) * 64;             // 8 m-tiles per j

  for (int layer = 0; layer < 2; ++layer) {
    f32x4 cv = {0.f, 0.f, 0.f, 0.f};
    if (layer == 1) {
      for (int idx = gtid; idx < B_ * H_; idx += NTHR) {
        sth_coh(hhi + idx, 0); sth_coh(hlo + idx, 0);
      }
      lbar(bar, nb);
    }
    for (int s = 0; s < SEQ_; ++s) {
      const int torig = SEQ_ - 1 - s;
      if (layer == 0) {
        g1_phase<false>(LDS, g1_m0, g1_n0, hhi, hlo, Wd0s, bd0,
                        Tm1T + (size_t)torig * B_, huhi, hulo,
                        nullptr, nullptr, nullptr);
        lbar(bar, nb);
        g2_phase<576, 64, SEQ_ * 64, true, false>(
            LDS, g2_m0, g2_j0,
            xinhi + (size_t)torig * 64, xinlo + (size_t)torig * 64,
            huhi, hulo, W0s, b0, cv, hhi, hlo,
            lo0 + (size_t)s * H_);
        lbar(bar, nb);
      } else {
        g1_phase<true>(LDS, g1_m0, g1_n0, hhi, hlo, Wd1s, bd1,
                       Tm1T + (size_t)torig * B_, huhi, hulo,
                       lo0 + (size_t)torig * H_, xhhi, xhlo);
        lbar(bar, nb);
        g2_phase<1024, 512, H_, false, true>(
            LDS, g2_m0, g2_j0,
            xhhi, xhlo, huhi, hulo, W1s, b1,
            cv, hhi, hlo, nullptr);
        lbar(bar, nb);
      }
    }
  }

  for (int idx = gtid; idx < B_ * H_; idx += NTHR)
    out[idx] = bf2f(ldh_coh((const unsigned short*)hhi + idx)) +
               bf2f(ldh_coh((const unsigned short*)hlo + idx));
}

extern "C" void kernel_launch(void* const* d_in, const int* in_sizes, int n_in,
                              void* d_out, int out_size, void* d_ws, size_t ws_size,
                              hipStream_t stream) {
  const float* inputs = (const float*)d_in[0];
  const float* W0  = (const float*)d_in[1];
  const float* b0  = (const float*)d_in[2];
  const float* Wd0 = (const float*)d_in[3];
  const float* bd0 = (const float*)d_in[4];
  const float* W1  = (const float*)d_in[5];
  const float* b1  = (const float*)d_in[6];
  const float* Wd1 = (const float*)d_in[7];
  const float* bd1 = (const float*)d_in[8];

  char* ws = (char*)d_ws;
  size_t off = 0;
  auto alloc = [&](size_t bytes) -> char* {
    char* p = ws + off;
    off += (bytes + 1023) & ~(size_t)1023;
    return p;
  };
  unsigned* bar = (unsigned*)alloc(2048);
  int* xcdmap = (int*)alloc(NBLK * 4);
  unsigned short* lo0 = (unsigned short*)alloc((size_t)B_ * SEQ_ * H_ * 2); // fp16
  short* xinhi = (short*)alloc((size_t)B_ * SEQ_ * 64 * 2);
  short* xinlo = (short*)alloc((size_t)B_ * SEQ_ * 64 * 2);
  short* hhi   = (short*)alloc((size_t)B_ * H_ * 2);
  short* hlo   = (short*)alloc((size_t)B_ * H_ * 2);
  short* huhi  = (short*)alloc((size_t)B_ * H_ * 2);
  short* hulo  = (short*)alloc((size_t)B_ * H_ * 2);
  short* xhhi  = (short*)alloc((size_t)B_ * H_ * 2);
  short* xhlo  = (short*)alloc((size_t)B_ * H_ * 2);
  float* Tm1T  = (float*)alloc((size_t)SEQ_ * B_ * 4);
  short* Wd0s  = (short*)alloc((size_t)512 * 1024 * 2);
  short* Wd1s  = (short*)alloc((size_t)512 * 1024 * 2);
  short* W0s   = (short*)alloc((size_t)2048 * 1152 * 2);
  short* W1s   = (short*)alloc((size_t)2048 * 2048 * 2);

  if (off > ws_size) {
    fill_kernel<<<(out_size + 255) / 256, 256, 0, stream>>>(
        (float*)d_out, out_size, (float)(ws_size >> 20));
    return;
  }

  hipMemsetAsync(bar, 0, 2048, stream);
  persist<<<NBLK, 256, 0, stream>>>(
      inputs, W0, b0, Wd0, bd0, W1, b1, Wd1, bd1,
      (float*)d_out,
      lo0, xinhi, xinlo,
      hhi, hlo, huhi, hulo, xhhi, xhlo,
      Tm1T, Wd0s, Wd1s, W0s, W1s, bar, xcdmap);
}